// Round 1
// baseline (1571.237 us; speedup 1.0000x reference)
//
#include <hip/hip_runtime.h>

// ============================================================================
// Decoder_70437463654609: 32-step LSTM recurrence, B=2048 H=512 HID=16.
// Strategy: fold se-MLP into W1f[16,2048] (kills the x@w_ih GEMM), persistent
// cooperative kernel with w_hh resident in LDS (bf16), one grid barrier/step.
// ============================================================================

#define TSEQ  32
#define BATCH 2048
#define HDIM  512
#define GDIM  2048   // 4*H
#define NBLK  256
#define NTHR  512

typedef __bf16 bf16x8 __attribute__((ext_vector_type(8)));
typedef float  f32x16 __attribute__((ext_vector_type(16)));

// ---- LDS layout (byte offsets), total 163584 <= 163840 (160 KiB) ----
#define BS_OFF     0          // Bs: w_hh slice [128 n][64 atoms x 16B], xor-swizzled (131072)
#define UNI_OFF    131072     // union: As [128][8 atoms] swz (16384) | hP [128][33] f32 (16896) | h2s [128][17] f32 (8704)
#define H1_OFF     147968     // h1s  [128 m][24 bf16] stride 48 B (6144)
#define W1_OFF     154112     // W1fs [128 n][24 bf16]             (6144)
#define HPW_OFF    160256     // hpw1s [32 jj][16 q] bf16          (1024)
#define BIASF_OFF  161280     // bias_fs [128] f32                 (512)
#define LPS_OFF    161792     // lps [128][2] f32                  (1024)
#define PRM_OFF    162816     // folded params (~130 f32)          (768)
#define LDS_TOTAL  163584

// ---- workspace layout (bytes); needs ~8.5 MB ----
#define WS_W1F    0                        // [2048][16] f32 : se_w2 @ w_ih^T
#define WS_BIASF  131072                   // [2048]     f32 : se_b2@w_ih^T + b_ih + b_hh
#define WS_BAR    139264                   // grid barrier counter
#define WS_HBF    139776                   // 2 x [2048][512] bf16 (h, double buffered)
#define WS_PART   (WS_HBF + 2*2097152)     // 2 x [2048][16 nt][16 q] f32 (hp partials)

__device__ __forceinline__ unsigned short f2bf(float f) {   // RNE f32->bf16
  unsigned u = __float_as_uint(f);
  u += 0x7fffu + ((u >> 16) & 1u);
  return (unsigned short)(u >> 16);
}
__device__ __forceinline__ float bf2f(unsigned short b) {
  return __uint_as_float(((unsigned)b) << 16);
}
__device__ __forceinline__ void gl_lds16(const void* g, void* l) {
  __builtin_amdgcn_global_load_lds((const __attribute__((address_space(1))) unsigned*)g,
                                   (__attribute__((address_space(3))) unsigned*)l, 16, 0, 0);
}
// quad-perm broadcast: all 4 lanes of a quad receive lane (base+IMM)'s value
#define QB(x, imm) __uint_as_float((unsigned)__builtin_amdgcn_mov_dpp((int)__float_as_uint(x), imm, 0xF, 0xF, true))

struct KParams {
  const float *last_pos, *ch0, *w_hh;
  const float *se_w1, *se_b1, *se_g, *se_bt, *se_m, *se_v;
  const float *hp_w1, *hp_b1, *hp_g, *hp_bt, *hp_m, *hp_v, *hp_w2, *hp_b2;
  const float *W1f_g, *bias_f;
  unsigned short* h_bf;   // 2 buffers
  float* part;            // 2 buffers
  unsigned* bar;
  float* out;
};

// ---------------------------------------------------------------------------
// Setup: W1f = se_w2 @ w_ih^T, fused bias, h0 -> bf16.  <<<4096, 64>>>
// ---------------------------------------------------------------------------
__global__ __launch_bounds__(64) void decoder_setup(
    const float* __restrict__ w_ih, const float* __restrict__ se_w2,
    const float* __restrict__ se_b2, const float* __restrict__ b_ih,
    const float* __restrict__ b_hh, const float* __restrict__ hh,
    float* __restrict__ W1f_g, float* __restrict__ bias_f,
    unsigned short* __restrict__ h_bf0) {
  int bid = blockIdx.x, tid = threadIdx.x;
  if (bid < GDIM) {
    const float* wrow = w_ih + (size_t)bid * 512;
    if (tid < 16) {
      const float* sw = se_w2 + (size_t)tid * 512;
      float s = 0.f;
      for (int e = 0; e < 512; ++e) s += sw[e] * wrow[e];
      W1f_g[bid * 16 + tid] = s;
    } else if (tid == 16) {
      float s = 0.f;
      for (int e = 0; e < 512; ++e) s += se_b2[e] * wrow[e];
      bias_f[bid] = s + b_ih[bid] + b_hh[bid];
    }
  } else {
    int m = bid - GDIM;                       // hh is [1,B,H] flat
    const float* src = hh + (size_t)m * 512 + tid * 8;
    uint4 v;
    v.x = (unsigned)f2bf(src[0]) | ((unsigned)f2bf(src[1]) << 16);
    v.y = (unsigned)f2bf(src[2]) | ((unsigned)f2bf(src[3]) << 16);
    v.z = (unsigned)f2bf(src[4]) | ((unsigned)f2bf(src[5]) << 16);
    v.w = (unsigned)f2bf(src[6]) | ((unsigned)f2bf(src[7]) << 16);
    *(uint4*)(h_bf0 + (size_t)m * 512 + tid * 8) = v;
  }
}

// ---------------------------------------------------------------------------
// Persistent kernel. 256 blocks x 512 threads, 1 block/CU (163584 B LDS).
// Block (mt, nt): rows [mt*128, +128), hidden cols [nt*32, +32) x 4 gates,
// local n = 4*jj + gate (gate = 0:i 1:f 2:g 3:o).
// ---------------------------------------------------------------------------
__global__ __launch_bounds__(NTHR, 2) void decoder_persist(KParams p) {
  extern __shared__ char lds[];
  const int tid  = threadIdx.x;
  const int lane = tid & 63;
  const int wid  = tid >> 6;          // 0..7
  const int wm   = wid >> 1;          // 0..3 : rows wm*32..+32
  const int wn   = wid & 1;           // 0..1 : cols wn*64..+64 (2 acc tiles)
  const int mt   = blockIdx.x >> 4;
  const int nt   = blockIdx.x & 15;
  const int m0   = mt * 128;

  float* prm    = (float*)(lds + PRM_OFF);
  float* biasf  = (float*)(lds + BIASF_OFF);
  float* lps    = (float*)(lds + LPS_OFF);
  unsigned short* h1s   = (unsigned short*)(lds + H1_OFF);
  unsigned short* W1fs  = (unsigned short*)(lds + W1_OFF);
  unsigned short* hpw1s = (unsigned short*)(lds + HPW_OFF);

  // ---------------- one-time init ----------------
  if (tid < 16) {
    int q = tid;
    float sA = p.se_g[q] * rsqrtf(p.se_v[q] + 1e-5f);
    prm[q]      = sA;
    prm[16 + q] = (p.se_b1[q] - p.se_m[q]) * sA + p.se_bt[q];
    float hA = p.hp_g[q] * rsqrtf(p.hp_v[q] + 1e-5f);
    prm[32 + q] = hA;
    prm[48 + q] = (p.hp_b1[q] - p.hp_m[q]) * hA + p.hp_bt[q];
  }
  if (tid < 32) { prm[64 + tid] = p.se_w1[tid]; prm[96 + tid] = p.hp_w2[tid]; }
  if (tid < 2)  { prm[128 + tid] = p.hp_b2[tid]; }
  for (int n = tid; n < 128; n += NTHR) {
    int grow = (n & 3) * 512 + nt * 32 + (n >> 2);
    biasf[n] = p.bias_f[grow];
  }
  for (int id = tid; id < 2048; id += NTHR) {       // W1fs [128][16] bf16 (stride 24)
    int n = id >> 4, q = id & 15;
    int grow = (n & 3) * 512 + nt * 32 + (n >> 2);
    W1fs[n * 24 + q] = f2bf(p.W1f_g[grow * 16 + q]);
  }
  for (int id = tid; id < 512; id += NTHR) {        // hpw1s [32][16]
    int jj = id >> 4, q = id & 15;
    hpw1s[id] = f2bf(p.hp_w1[(nt * 32 + jj) * 16 + q]);
  }
  if (tid < 256) lps[tid] = p.last_pos[(size_t)m0 * 2 + tid];
  // Bs: w_hh slice -> bf16, atoms (n, ka) stored at n*64 + (ka ^ (n&7))
  for (int a = tid; a < 8192; a += NTHR) {
    int n = a >> 6, ka = a & 63;
    int grow = (n & 3) * 512 + nt * 32 + (n >> 2);
    const float* src = p.w_hh + (size_t)grow * 512 + ka * 8;
    uint4 v;
    v.x = (unsigned)f2bf(src[0]) | ((unsigned)f2bf(src[1]) << 16);
    v.y = (unsigned)f2bf(src[2]) | ((unsigned)f2bf(src[3]) << 16);
    v.z = (unsigned)f2bf(src[4]) | ((unsigned)f2bf(src[5]) << 16);
    v.w = (unsigned)f2bf(src[6]) | ((unsigned)f2bf(src[7]) << 16);
    *(uint4*)(lds + BS_OFF + ((size_t)(n * 64 + (ka ^ (n & 7)))) * 16) = v;
  }
  // c state in registers (valid on lanes with lane%4==0; 16 (row) x 2 (tile))
  float c_st[2][16];
  #pragma unroll
  for (int t2 = 0; t2 < 2; ++t2)
    #pragma unroll
    for (int r = 0; r < 16; ++r) c_st[t2][r] = 0.f;
  if ((lane & 3) == 0) {
    #pragma unroll
    for (int t2 = 0; t2 < 2; ++t2) {
      int n_loc = wn * 64 + t2 * 32 + (lane & 31);
      int jj = n_loc >> 2;
      #pragma unroll
      for (int r = 0; r < 16; ++r) {
        int row = (r & 3) + 8 * (r >> 2) + 4 * (lane >> 5) + wm * 32;
        c_st[t2][r] = p.ch0[(size_t)(m0 + row) * 512 + nt * 32 + jj];
      }
    }
  }
  __syncthreads();

  const int n0 = wn * 64 + (lane & 31);
  const int n1 = n0 + 32;
  const int gate = lane & 3;

  for (int t = 0; t <= TSEQ; ++t) {
    const int cur = t & 1, nxt = cur ^ 1, prv = cur ^ 1;   // (t-1)&1 == cur^1

    // ---------- prologue: lp_t = sigmoid(MLP2(h_t) + lp_{t-1}), traj[t-1] ----------
    if (t > 0) {
      float* h2s = (float*)(lds + UNI_OFF);                // [128][17]
      const float* pin = p.part + (size_t)prv * BATCH * 256;
      #pragma unroll
      for (int u = 0; u < 4; ++u) {
        int id = u * NTHR + tid;                           // 128 m x 16 q
        int m = id >> 4, q = id & 15;
        const float* base = pin + (size_t)(m0 + m) * 256 + q;
        float s = 0.f;
        #pragma unroll
        for (int j = 0; j < 16; ++j) s += base[j * 16];
        float hv = s * prm[32 + q] + prm[48 + q];
        h2s[m * 17 + q] = fmaxf(hv, 0.f);
      }
      __syncthreads();
      if (tid < 256) {
        int m = tid >> 1, c = tid & 1;
        float a2 = prm[128 + c];
        #pragma unroll
        for (int q = 0; q < 16; ++q) a2 += h2s[m * 17 + q] * prm[96 + q * 2 + c];
        float lpv = 1.f / (1.f + __expf(-(a2 + lps[tid])));
        lps[tid] = lpv;
        if (nt == 0) p.out[((size_t)(t - 1) * BATCH + m0 + m) * 2 + c] = lpv;
      }
      __syncthreads();
    }
    if (t == TSEQ) break;

    // ---------- h1 = relu(affine(lp @ se_w1)) ----------
    #pragma unroll
    for (int u = 0; u < 4; ++u) {
      int id = u * NTHR + tid;
      int m = id >> 4, q = id & 15;
      float z = lps[m * 2] * prm[64 + q] + lps[m * 2 + 1] * prm[80 + q];
      h1s[m * 24 + q] = f2bf(fmaxf(z * prm[q] + prm[16 + q], 0.f));
    }
    __syncthreads();

    // ---------- acc init: xg = h1 @ W1f (K=16, one MFMA per tile) ----------
    f32x16 acc0, acc1;
    {
      f32x16 z;
      #pragma unroll
      for (int i = 0; i < 16; ++i) z[i] = 0.f;
      int mrow = wm * 32 + (lane & 31);
      bf16x8 av = *(const bf16x8*)((char*)h1s + mrow * 48 + (lane >> 5) * 16);
      bf16x8 b0 = *(const bf16x8*)((char*)W1fs + n0 * 48 + (lane >> 5) * 16);
      bf16x8 b1 = *(const bf16x8*)((char*)W1fs + n1 * 48 + (lane >> 5) * 16);
      acc0 = __builtin_amdgcn_mfma_f32_32x32x16_bf16(av, b0, z, 0, 0, 0);
      acc1 = __builtin_amdgcn_mfma_f32_32x32x16_bf16(av, b1, z, 0, 0, 0);
    }

    // ---------- main GEMM: gates += h_prev @ w_hh^T ----------
    const unsigned short* hsrc = p.h_bf + (size_t)cur * BATCH * HDIM;
    for (int kc = 0; kc < 8; ++kc) {
      __syncthreads();                                     // As region free
      #pragma unroll
      for (int u = 0; u < 2; ++u) {                        // stage As [128 m][64 k]
        int s = u * NTHR + tid;
        int m = s >> 3, kl = s & 7;
        int kg = kl ^ (m & 7);                             // xor-swizzle
        gl_lds16(hsrc + (size_t)(m0 + m) * 512 + kc * 64 + kg * 8,
                 lds + UNI_OFF + s * 16);
      }
      __syncthreads();
      #pragma unroll
      for (int k16 = 0; k16 < 4; ++k16) {
        int mrow = wm * 32 + (lane & 31);
        int ka = k16 * 2 + (lane >> 5);
        bf16x8 av = *(const bf16x8*)(lds + UNI_OFF + ((mrow << 3) + (ka ^ (mrow & 7))) * 16);
        int kal = kc * 8 + ka;
        bf16x8 b0 = *(const bf16x8*)(lds + BS_OFF + ((n0 << 6) + (kal ^ (n0 & 7))) * 16);
        bf16x8 b1 = *(const bf16x8*)(lds + BS_OFF + ((n1 << 6) + (kal ^ (n1 & 7))) * 16);
        acc0 = __builtin_amdgcn_mfma_f32_32x32x16_bf16(av, b0, acc0, 0, 0, 0);
        acc1 = __builtin_amdgcn_mfma_f32_32x32x16_bf16(av, b1, acc1, 0, 0, 0);
      }
    }
    __syncthreads();   // all As reads done before hP overwrites the region

    // ---------- epilogue: LSTM cell update (quad-lane exchange via DPP) ----------
    float* hP = (float*)(lds + UNI_OFF);                   // [128][33]
    #pragma unroll
    for (int t2 = 0; t2 < 2; ++t2) {
      int n_loc = wn * 64 + t2 * 32 + (lane & 31);
      float bias = biasf[n_loc];
      int jj = n_loc >> 2;
      float act[16];
      const f32x16& A = (t2 == 0) ? acc0 : acc1;
      #pragma unroll
      for (int r = 0; r < 16; ++r) {
        float v = A[r] + bias;
        float vv = (gate == 2) ? 2.f * v : v;
        float sg = 1.f / (1.f + __expf(-vv));
        act[r] = (gate == 2) ? 2.f * sg - 1.f : sg;
      }
      #pragma unroll
      for (int r = 0; r < 16; ++r) {
        float iv = QB(act[r], 0x00);
        float fv = QB(act[r], 0x55);
        float gv = QB(act[r], 0xAA);
        float ov = QB(act[r], 0xFF);
        float cn = fv * c_st[t2][r] + iv * gv;
        c_st[t2][r] = cn;
        float th = 2.f / (1.f + __expf(-2.f * cn)) - 1.f;
        float hn = ov * th;
        if ((lane & 3) == 0) {
          int row = (r & 3) + 8 * (r >> 2) + 4 * (lane >> 5) + wm * 32;
          hP[row * 33 + jj] = hn;
        }
      }
    }
    __syncthreads();

    // ---------- write h (bf16, next buffer) + hp partial sums ----------
    unsigned short* hdst = p.h_bf + (size_t)nxt * BATCH * HDIM;
    #pragma unroll
    for (int u = 0; u < 4; ++u) {
      int id = u * NTHR + tid;                             // 128 m x 16 pairs
      int m = id >> 4, cp = id & 15;
      unsigned pk = (unsigned)f2bf(hP[m * 33 + cp * 2]) |
                    ((unsigned)f2bf(hP[m * 33 + cp * 2 + 1]) << 16);
      *(unsigned*)(hdst + (size_t)(m0 + m) * 512 + nt * 32 + cp * 2) = pk;
    }
    float* pdst = p.part + (size_t)cur * BATCH * 256;
    #pragma unroll
    for (int u = 0; u < 4; ++u) {
      int id = u * NTHR + tid;                             // 128 m x 16 q
      int m = id >> 4, q = id & 15;
      float s = 0.f;
      #pragma unroll
      for (int jj = 0; jj < 32; ++jj) s += hP[m * 33 + jj] * bf2f(hpw1s[jj * 16 + q]);
      pdst[(size_t)(m0 + m) * 256 + nt * 16 + q] = s;
    }

    // ---------- grid barrier (monotone counter; all 256 blocks co-resident) ----------
    __syncthreads();
    if (tid == 0) {
      __threadfence();
      __hip_atomic_fetch_add(p.bar, 1u, __ATOMIC_ACQ_REL, __HIP_MEMORY_SCOPE_AGENT);
      unsigned target = (unsigned)NBLK * (unsigned)(t + 1);
      while (__hip_atomic_load(p.bar, __ATOMIC_ACQUIRE, __HIP_MEMORY_SCOPE_AGENT) < target)
        __builtin_amdgcn_s_sleep(2);
    }
    __syncthreads();
  }
}

// ---------------------------------------------------------------------------
extern "C" void kernel_launch(void* const* d_in, const int* in_sizes, int n_in,
                              void* d_out, int out_size, void* d_ws, size_t ws_size,
                              hipStream_t stream) {
  char* ws = (char*)d_ws;
  const float* last_pos = (const float*)d_in[0];
  const float* hh    = (const float*)d_in[1];
  const float* ch    = (const float*)d_in[2];
  const float* se_w1 = (const float*)d_in[3];
  const float* se_b1 = (const float*)d_in[4];
  const float* se_g  = (const float*)d_in[5];
  const float* se_bt = (const float*)d_in[6];
  const float* se_m  = (const float*)d_in[7];
  const float* se_v  = (const float*)d_in[8];
  const float* se_w2 = (const float*)d_in[9];
  const float* se_b2 = (const float*)d_in[10];
  const float* w_ih  = (const float*)d_in[11];
  const float* w_hh  = (const float*)d_in[12];
  const float* b_ih  = (const float*)d_in[13];
  const float* b_hh  = (const float*)d_in[14];
  const float* hp_w1 = (const float*)d_in[15];
  const float* hp_b1 = (const float*)d_in[16];
  const float* hp_g  = (const float*)d_in[17];
  const float* hp_bt = (const float*)d_in[18];
  const float* hp_m  = (const float*)d_in[19];
  const float* hp_v  = (const float*)d_in[20];
  const float* hp_w2 = (const float*)d_in[21];
  const float* hp_b2 = (const float*)d_in[22];

  float* W1f_g  = (float*)(ws + WS_W1F);
  float* bias_f = (float*)(ws + WS_BIASF);
  unsigned* bar = (unsigned*)(ws + WS_BAR);
  unsigned short* h_bf = (unsigned short*)(ws + WS_HBF);
  float* part   = (float*)(ws + WS_PART);

  hipMemsetAsync(ws + WS_BAR, 0, 256, stream);
  decoder_setup<<<dim3(2 * GDIM), dim3(64), 0, stream>>>(
      w_ih, se_w2, se_b2, b_ih, b_hh, hh, W1f_g, bias_f, h_bf);

  hipFuncSetAttribute((const void*)decoder_persist,
                      hipFuncAttributeMaxDynamicSharedMemorySize, LDS_TOTAL);

  KParams kp;
  kp.last_pos = last_pos; kp.ch0 = ch; kp.w_hh = w_hh;
  kp.se_w1 = se_w1; kp.se_b1 = se_b1; kp.se_g = se_g; kp.se_bt = se_bt;
  kp.se_m = se_m; kp.se_v = se_v;
  kp.hp_w1 = hp_w1; kp.hp_b1 = hp_b1; kp.hp_g = hp_g; kp.hp_bt = hp_bt;
  kp.hp_m = hp_m; kp.hp_v = hp_v; kp.hp_w2 = hp_w2; kp.hp_b2 = hp_b2;
  kp.W1f_g = W1f_g; kp.bias_f = bias_f;
  kp.h_bf = h_bf; kp.part = part; kp.bar = bar; kp.out = (float*)d_out;

  void* args[] = { &kp };
  hipLaunchCooperativeKernel((void*)decoder_persist, dim3(NBLK), dim3(NTHR),
                             args, LDS_TOTAL, stream);
}

// Round 2
// 1429.271 us; speedup vs baseline: 1.0993x; 1.0993x over previous
//
#include <hip/hip_runtime.h>

// ============================================================================
// Decoder_70437463654609: 32-step LSTM recurrence, B=2048 H=512 HID=16.
// R2: (1) relaxed sc0/sc1 atomics for all cross-block data + barrier (no
//     buffer_inv/wbl2 storms), (2) register-pipelined A fragments (no LDS As
//     staging, no inner barriers), (3) 8B-packed partials.
// ============================================================================

#define TSEQ  32
#define BATCH 2048
#define HDIM  512
#define GDIM  2048   // 4*H
#define NBLK  256
#define NTHR  512
#define DEPTH 12     // A-fragment prefetch pipeline depth (chunks of K=16)

typedef __bf16 bf16x8 __attribute__((ext_vector_type(8)));
typedef float  f32x16 __attribute__((ext_vector_type(16)));
typedef unsigned long long u64;

// ---- LDS layout (byte offsets), total 163584 <= 163840 (160 KiB) ----
#define BS_OFF     0          // Bs: w_hh slice [128 n][64 atoms x 16B], xor-swizzled (131072)
#define UNI_OFF    131072     // union: hP [128][33] f32 (16896) | h2s [128][16] f32 (8192)
#define H1_OFF     147968     // h1s  [128 m][24 bf16] stride 48 B (6144)
#define W1_OFF     154112     // W1fs [128 n][24 bf16]             (6144)
#define HPW_OFF    160256     // hpw1s [32 jj][16 q] bf16          (1024)
#define BIASF_OFF  161280     // bias_fs [128] f32                 (512)
#define LPS_OFF    161792     // lps [128][2] f32                  (1024)
#define PRM_OFF    162816     // folded params (~130 f32)          (768)
#define LDS_TOTAL  163584

// ---- workspace layout (bytes) ----
#define WS_W1F    0                        // [2048][16] f32 : se_w2 @ w_ih^T
#define WS_BIASF  131072                   // [2048]     f32 : se_b2@w_ih^T + b_ih + b_hh
#define WS_BAR    139264                   // grid barrier counter
#define WS_HBF    139776                   // 2 x [2048][512] bf16 (h, double buffered)
#define WS_PART   (WS_HBF + 2*2097152)     // 2 x [2048][16 j][8 qp] u64 (hp partials, f32 pairs)

__device__ __forceinline__ unsigned short f2bf(float f) {   // RNE f32->bf16
  unsigned u = __float_as_uint(f);
  u += 0x7fffu + ((u >> 16) & 1u);
  return (unsigned short)(u >> 16);
}
__device__ __forceinline__ float bf2f(unsigned short b) {
  return __uint_as_float(((unsigned)b) << 16);
}
// relaxed agent-scope 8B load/store -> global_load/store_dwordx2 sc0 sc1
// (device-coherent, no cache-wide maintenance ops)
__device__ __forceinline__ u64 ld8(const void* p) {
  return __hip_atomic_load((const u64*)p, __ATOMIC_RELAXED, __HIP_MEMORY_SCOPE_AGENT);
}
__device__ __forceinline__ void st8(void* p, u64 v) {
  __hip_atomic_store((u64*)p, v, __ATOMIC_RELAXED, __HIP_MEMORY_SCOPE_AGENT);
}
__device__ __forceinline__ float lo32(u64 v) { return __uint_as_float((unsigned)v); }
__device__ __forceinline__ float hi32(u64 v) { return __uint_as_float((unsigned)(v >> 32)); }

// quad-perm broadcast: all 4 lanes of a quad receive lane (base+IMM)'s value
#define QB(x, imm) __uint_as_float((unsigned)__builtin_amdgcn_mov_dpp((int)__float_as_uint(x), imm, 0xF, 0xF, true))

struct KParams {
  const float *last_pos, *ch0, *w_hh;
  const float *se_w1, *se_b1, *se_g, *se_bt, *se_m, *se_v;
  const float *hp_w1, *hp_b1, *hp_g, *hp_bt, *hp_m, *hp_v, *hp_w2, *hp_b2;
  const float *W1f_g, *bias_f;
  unsigned short* h_bf;   // 2 buffers
  u64* part;              // 2 buffers
  unsigned* bar;
  float* out;
};

// ---------------------------------------------------------------------------
// Setup: W1f = se_w2 @ w_ih^T, fused bias, h0 -> bf16.  <<<4096, 64>>>
// ---------------------------------------------------------------------------
__global__ __launch_bounds__(64) void decoder_setup(
    const float* __restrict__ w_ih, const float* __restrict__ se_w2,
    const float* __restrict__ se_b2, const float* __restrict__ b_ih,
    const float* __restrict__ b_hh, const float* __restrict__ hh,
    float* __restrict__ W1f_g, float* __restrict__ bias_f,
    unsigned short* __restrict__ h_bf0) {
  int bid = blockIdx.x, tid = threadIdx.x;
  if (bid < GDIM) {
    const float* wrow = w_ih + (size_t)bid * 512;
    if (tid < 16) {
      const float* sw = se_w2 + (size_t)tid * 512;
      float s = 0.f;
      for (int e = 0; e < 512; ++e) s += sw[e] * wrow[e];
      W1f_g[bid * 16 + tid] = s;
    } else if (tid == 16) {
      float s = 0.f;
      for (int e = 0; e < 512; ++e) s += se_b2[e] * wrow[e];
      bias_f[bid] = s + b_ih[bid] + b_hh[bid];
    }
  } else {
    int m = bid - GDIM;                       // hh is [1,B,H] flat
    const float* src = hh + (size_t)m * 512 + tid * 8;
    uint4 v;
    v.x = (unsigned)f2bf(src[0]) | ((unsigned)f2bf(src[1]) << 16);
    v.y = (unsigned)f2bf(src[2]) | ((unsigned)f2bf(src[3]) << 16);
    v.z = (unsigned)f2bf(src[4]) | ((unsigned)f2bf(src[5]) << 16);
    v.w = (unsigned)f2bf(src[6]) | ((unsigned)f2bf(src[7]) << 16);
    *(uint4*)(h_bf0 + (size_t)m * 512 + tid * 8) = v;
  }
}

// ---------------------------------------------------------------------------
// Persistent kernel. 256 blocks x 512 threads, 1 block/CU.
// Block (mt, nt): rows [mt*128, +128), hidden cols [nt*32, +32) x 4 gates,
// local n = 4*jj + gate (gate = 0:i 1:f 2:g 3:o).
// ---------------------------------------------------------------------------
__global__ __launch_bounds__(NTHR, 2) void decoder_persist(KParams p) {
  extern __shared__ char lds[];
  const int tid  = threadIdx.x;
  const int lane = tid & 63;
  const int wid  = tid >> 6;          // 0..7
  const int wm   = wid >> 1;          // 0..3 : rows wm*32..+32
  const int wn   = wid & 1;           // 0..1 : cols wn*64..+64 (2 acc tiles)
  const int mt   = blockIdx.x >> 4;
  const int nt   = blockIdx.x & 15;
  const int m0   = mt * 128;

  float* prm    = (float*)(lds + PRM_OFF);
  float* biasf  = (float*)(lds + BIASF_OFF);
  float* lps    = (float*)(lds + LPS_OFF);
  unsigned short* h1s   = (unsigned short*)(lds + H1_OFF);
  unsigned short* W1fs  = (unsigned short*)(lds + W1_OFF);
  unsigned short* hpw1s = (unsigned short*)(lds + HPW_OFF);

  // ---------------- one-time init ----------------
  if (tid < 16) {
    int q = tid;
    float sA = p.se_g[q] * rsqrtf(p.se_v[q] + 1e-5f);
    prm[q]      = sA;
    prm[16 + q] = (p.se_b1[q] - p.se_m[q]) * sA + p.se_bt[q];
    float hA = p.hp_g[q] * rsqrtf(p.hp_v[q] + 1e-5f);
    prm[32 + q] = hA;
    prm[48 + q] = (p.hp_b1[q] - p.hp_m[q]) * hA + p.hp_bt[q];
  }
  if (tid < 32) { prm[64 + tid] = p.se_w1[tid]; prm[96 + tid] = p.hp_w2[tid]; }
  if (tid < 2)  { prm[128 + tid] = p.hp_b2[tid]; }
  for (int n = tid; n < 128; n += NTHR) {
    int grow = (n & 3) * 512 + nt * 32 + (n >> 2);
    biasf[n] = p.bias_f[grow];
  }
  for (int id = tid; id < 2048; id += NTHR) {       // W1fs [128][16] bf16 (stride 24)
    int n = id >> 4, q = id & 15;
    int grow = (n & 3) * 512 + nt * 32 + (n >> 2);
    W1fs[n * 24 + q] = f2bf(p.W1f_g[grow * 16 + q]);
  }
  for (int id = tid; id < 512; id += NTHR) {        // hpw1s [32][16]
    int jj = id >> 4, q = id & 15;
    hpw1s[id] = f2bf(p.hp_w1[(nt * 32 + jj) * 16 + q]);
  }
  if (tid < 256) lps[tid] = p.last_pos[(size_t)m0 * 2 + tid];
  // Bs: w_hh slice -> bf16, atoms (n, ka) stored at n*64 + (ka ^ (n&7))
  for (int a = tid; a < 8192; a += NTHR) {
    int n = a >> 6, ka = a & 63;
    int grow = (n & 3) * 512 + nt * 32 + (n >> 2);
    const float* src = p.w_hh + (size_t)grow * 512 + ka * 8;
    uint4 v;
    v.x = (unsigned)f2bf(src[0]) | ((unsigned)f2bf(src[1]) << 16);
    v.y = (unsigned)f2bf(src[2]) | ((unsigned)f2bf(src[3]) << 16);
    v.z = (unsigned)f2bf(src[4]) | ((unsigned)f2bf(src[5]) << 16);
    v.w = (unsigned)f2bf(src[6]) | ((unsigned)f2bf(src[7]) << 16);
    *(uint4*)(lds + BS_OFF + ((size_t)(n * 64 + (ka ^ (n & 7)))) * 16) = v;
  }
  // c state in registers (valid on lanes with lane%4==0; 16 (row) x 2 (tile))
  float c_st[2][16];
  #pragma unroll
  for (int t2 = 0; t2 < 2; ++t2)
    #pragma unroll
    for (int r = 0; r < 16; ++r) c_st[t2][r] = 0.f;
  if ((lane & 3) == 0) {
    #pragma unroll
    for (int t2 = 0; t2 < 2; ++t2) {
      int n_loc = wn * 64 + t2 * 32 + (lane & 31);
      int jj = n_loc >> 2;
      #pragma unroll
      for (int r = 0; r < 16; ++r) {
        int row = (r & 3) + 8 * (r >> 2) + 4 * (lane >> 5) + wm * 32;
        c_st[t2][r] = p.ch0[(size_t)(m0 + row) * 512 + nt * 32 + jj];
      }
    }
  }
  __syncthreads();

  const int n0 = wn * 64 + (lane & 31);
  const int n1 = n0 + 32;
  const int gate = lane & 3;
  // A-fragment base (u64 units): row = m0 + wm*32 + (lane&31), sub = lane>>5
  const int arow = m0 + wm * 32 + (lane & 31);
  const int asub = (lane >> 5) * 2;

  for (int t = 0; t <= TSEQ; ++t) {
    const int cur = t & 1, nxt = cur ^ 1, prv = cur ^ 1;   // (t-1)&1 == cur^1

    // ---------- prologue: lp_t = sigmoid(MLP2(h_t) + lp_{t-1}), traj[t-1] ----------
    if (t > 0) {
      float* h2s = (float*)(lds + UNI_OFF);                // [128][16]
      const u64* pin = p.part + (size_t)prv * BATCH * 128;
      #pragma unroll
      for (int u = 0; u < 2; ++u) {
        int id = u * NTHR + tid;                           // 128 m x 8 qp
        int m = id >> 3, qp = id & 7, q = qp * 2;
        const u64* base = pin + (size_t)(m0 + m) * 128 + qp;
        float s0 = 0.f, s1 = 0.f;
        #pragma unroll
        for (int j = 0; j < 16; ++j) {
          u64 x = ld8(base + j * 8);
          s0 += lo32(x); s1 += hi32(x);
        }
        float hv0 = s0 * prm[32 + q] + prm[48 + q];
        float hv1 = s1 * prm[33 + q] + prm[49 + q];
        h2s[m * 16 + q]     = fmaxf(hv0, 0.f);
        h2s[m * 16 + q + 1] = fmaxf(hv1, 0.f);
      }
      __syncthreads();
      if (tid < 256) {
        int m = tid >> 1, c = tid & 1;
        float a2 = prm[128 + c];
        #pragma unroll
        for (int q = 0; q < 16; ++q) a2 += h2s[m * 16 + q] * prm[96 + q * 2 + c];
        float lpv = 1.f / (1.f + __expf(-(a2 + lps[tid])));
        lps[tid] = lpv;
        if (nt == 0) p.out[((size_t)(t - 1) * BATCH + m0 + m) * 2 + c] = lpv;
      }
      __syncthreads();
    }
    if (t == TSEQ) break;

    // ---------- h1 = relu(affine(lp @ se_w1)) ----------
    #pragma unroll
    for (int u = 0; u < 4; ++u) {
      int id = u * NTHR + tid;
      int m = id >> 4, q = id & 15;
      float z = lps[m * 2] * prm[64 + q] + lps[m * 2 + 1] * prm[80 + q];
      h1s[m * 24 + q] = f2bf(fmaxf(z * prm[q] + prm[16 + q], 0.f));
    }
    __syncthreads();

    // ---------- acc init: xg = h1 @ W1f (K=16, one MFMA per tile) ----------
    f32x16 acc0, acc1;
    {
      f32x16 z;
      #pragma unroll
      for (int i = 0; i < 16; ++i) z[i] = 0.f;
      int mrow = wm * 32 + (lane & 31);
      bf16x8 av = *(const bf16x8*)((char*)h1s + mrow * 48 + (lane >> 5) * 16);
      bf16x8 b0 = *(const bf16x8*)((char*)W1fs + n0 * 48 + (lane >> 5) * 16);
      bf16x8 b1 = *(const bf16x8*)((char*)W1fs + n1 * 48 + (lane >> 5) * 16);
      acc0 = __builtin_amdgcn_mfma_f32_32x32x16_bf16(av, b0, z, 0, 0, 0);
      acc1 = __builtin_amdgcn_mfma_f32_32x32x16_bf16(av, b1, z, 0, 0, 0);
    }

    // ---------- main GEMM: gates += h_prev @ w_hh^T (A in registers) ----------
    {
      const u64* hq = (const u64*)(p.h_bf + (size_t)cur * BATCH * HDIM)
                      + (size_t)arow * 128 + asub;
      u64 pa[DEPTH], pb[DEPTH];
      #pragma unroll
      for (int c = 0; c < DEPTH; ++c) {
        pa[c] = ld8(hq + c * 4);
        pb[c] = ld8(hq + c * 4 + 1);
      }
      union AB { u64 q[2]; bf16x8 v; };
      #pragma unroll
      for (int c = 0; c < 32; ++c) {
        AB u;
        u.q[0] = pa[c % DEPTH];
        u.q[1] = pb[c % DEPTH];
        if (c + DEPTH < 32) {
          pa[c % DEPTH] = ld8(hq + (c + DEPTH) * 4);
          pb[c % DEPTH] = ld8(hq + (c + DEPTH) * 4 + 1);
        }
        int kal = c * 2 + (lane >> 5);
        bf16x8 b0 = *(const bf16x8*)(lds + BS_OFF + ((n0 << 6) + (kal ^ (n0 & 7))) * 16);
        bf16x8 b1 = *(const bf16x8*)(lds + BS_OFF + ((n1 << 6) + (kal ^ (n1 & 7))) * 16);
        acc0 = __builtin_amdgcn_mfma_f32_32x32x16_bf16(u.v, b0, acc0, 0, 0, 0);
        acc1 = __builtin_amdgcn_mfma_f32_32x32x16_bf16(u.v, b1, acc1, 0, 0, 0);
      }
    }

    // ---------- epilogue: LSTM cell update (quad-lane exchange via DPP) ----------
    float* hP = (float*)(lds + UNI_OFF);                   // [128][33]
    #pragma unroll
    for (int t2 = 0; t2 < 2; ++t2) {
      int n_loc = wn * 64 + t2 * 32 + (lane & 31);
      float bias = biasf[n_loc];
      int jj = n_loc >> 2;
      float act[16];
      const f32x16& A = (t2 == 0) ? acc0 : acc1;
      #pragma unroll
      for (int r = 0; r < 16; ++r) {
        float v = A[r] + bias;
        float vv = (gate == 2) ? 2.f * v : v;
        float sg = 1.f / (1.f + __expf(-vv));
        act[r] = (gate == 2) ? 2.f * sg - 1.f : sg;
      }
      #pragma unroll
      for (int r = 0; r < 16; ++r) {
        float iv = QB(act[r], 0x00);
        float fv = QB(act[r], 0x55);
        float gv = QB(act[r], 0xAA);
        float ov = QB(act[r], 0xFF);
        float cn = fv * c_st[t2][r] + iv * gv;
        c_st[t2][r] = cn;
        float th = 2.f / (1.f + __expf(-2.f * cn)) - 1.f;
        float hn = ov * th;
        if ((lane & 3) == 0) {
          int row = (r & 3) + 8 * (r >> 2) + 4 * (lane >> 5) + wm * 32;
          hP[row * 33 + jj] = hn;
        }
      }
    }
    __syncthreads();

    // ---------- write h (bf16, next buffer) + hp partial sums (sc1 stores) ----------
    unsigned short* hdst = p.h_bf + (size_t)nxt * BATCH * HDIM;
    #pragma unroll
    for (int u = 0; u < 2; ++u) {
      int id = u * NTHR + tid;                             // 128 m x 8 groups of 4 cols
      int m = id >> 3, grp = id & 7;
      u64 pk = (u64)f2bf(hP[m * 33 + grp * 4])
             | ((u64)f2bf(hP[m * 33 + grp * 4 + 1]) << 16)
             | ((u64)f2bf(hP[m * 33 + grp * 4 + 2]) << 32)
             | ((u64)f2bf(hP[m * 33 + grp * 4 + 3]) << 48);
      st8(hdst + (size_t)(m0 + m) * 512 + nt * 32 + grp * 4, pk);
    }
    u64* pdst = p.part + (size_t)cur * BATCH * 128;
    #pragma unroll
    for (int u = 0; u < 2; ++u) {
      int id = u * NTHR + tid;                             // 128 m x 8 qp
      int m = id >> 3, qp = id & 7, q = qp * 2;
      float s0 = 0.f, s1 = 0.f;
      #pragma unroll
      for (int jj = 0; jj < 32; ++jj) {
        float h = hP[m * 33 + jj];
        s0 += h * bf2f(hpw1s[jj * 16 + q]);
        s1 += h * bf2f(hpw1s[jj * 16 + q + 1]);
      }
      u64 pk = (u64)__float_as_uint(s0) | ((u64)__float_as_uint(s1) << 32);
      st8(pdst + (size_t)(m0 + m) * 128 + nt * 8 + qp, pk);
    }

    // ---------- grid barrier (relaxed atomics; data is sc1 write-through) ----------
    __asm__ volatile("s_waitcnt vmcnt(0)" ::: "memory");   // drain my sc1 stores
    __syncthreads();                                       // all waves drained
    if (tid == 0) {
      __hip_atomic_fetch_add(p.bar, 1u, __ATOMIC_RELAXED, __HIP_MEMORY_SCOPE_AGENT);
      unsigned target = (unsigned)NBLK * (unsigned)(t + 1);
      while (__hip_atomic_load(p.bar, __ATOMIC_RELAXED, __HIP_MEMORY_SCOPE_AGENT) < target)
        __builtin_amdgcn_s_sleep(1);
    }
    __syncthreads();
  }
}

// ---------------------------------------------------------------------------
extern "C" void kernel_launch(void* const* d_in, const int* in_sizes, int n_in,
                              void* d_out, int out_size, void* d_ws, size_t ws_size,
                              hipStream_t stream) {
  char* ws = (char*)d_ws;
  const float* last_pos = (const float*)d_in[0];
  const float* hh    = (const float*)d_in[1];
  const float* ch    = (const float*)d_in[2];
  const float* se_w1 = (const float*)d_in[3];
  const float* se_b1 = (const float*)d_in[4];
  const float* se_g  = (const float*)d_in[5];
  const float* se_bt = (const float*)d_in[6];
  const float* se_m  = (const float*)d_in[7];
  const float* se_v  = (const float*)d_in[8];
  const float* se_w2 = (const float*)d_in[9];
  const float* se_b2 = (const float*)d_in[10];
  const float* w_ih  = (const float*)d_in[11];
  const float* w_hh  = (const float*)d_in[12];
  const float* b_ih  = (const float*)d_in[13];
  const float* b_hh  = (const float*)d_in[14];
  const float* hp_w1 = (const float*)d_in[15];
  const float* hp_b1 = (const float*)d_in[16];
  const float* hp_g  = (const float*)d_in[17];
  const float* hp_bt = (const float*)d_in[18];
  const float* hp_m  = (const float*)d_in[19];
  const float* hp_v  = (const float*)d_in[20];
  const float* hp_w2 = (const float*)d_in[21];
  const float* hp_b2 = (const float*)d_in[22];

  float* W1f_g  = (float*)(ws + WS_W1F);
  float* bias_f = (float*)(ws + WS_BIASF);
  unsigned* bar = (unsigned*)(ws + WS_BAR);
  unsigned short* h_bf = (unsigned short*)(ws + WS_HBF);
  u64* part     = (u64*)(ws + WS_PART);

  hipMemsetAsync(ws + WS_BAR, 0, 256, stream);
  decoder_setup<<<dim3(2 * GDIM), dim3(64), 0, stream>>>(
      w_ih, se_w2, se_b2, b_ih, b_hh, hh, W1f_g, bias_f, h_bf);

  hipFuncSetAttribute((const void*)decoder_persist,
                      hipFuncAttributeMaxDynamicSharedMemorySize, LDS_TOTAL);

  KParams kp;
  kp.last_pos = last_pos; kp.ch0 = ch; kp.w_hh = w_hh;
  kp.se_w1 = se_w1; kp.se_b1 = se_b1; kp.se_g = se_g; kp.se_bt = se_bt;
  kp.se_m = se_m; kp.se_v = se_v;
  kp.hp_w1 = hp_w1; kp.hp_b1 = hp_b1; kp.hp_g = hp_g; kp.hp_bt = hp_bt;
  kp.hp_m = hp_m; kp.hp_v = hp_v; kp.hp_w2 = hp_w2; kp.hp_b2 = hp_b2;
  kp.W1f_g = W1f_g; kp.bias_f = bias_f;
  kp.h_bf = h_bf; kp.part = part; kp.bar = bar; kp.out = (float*)d_out;

  void* args[] = { &kp };
  hipLaunchCooperativeKernel((void*)decoder_persist, dim3(NBLK), dim3(NTHR),
                             args, LDS_TOTAL, stream);
}

// Round 3
// 1254.994 us; speedup vs baseline: 1.2520x; 1.1389x over previous
//
#include <hip/hip_runtime.h>

// ============================================================================
// Decoder_70437463654609: 32-step LSTM recurrence, B=2048 H=512 HID=16.
// R3: (1) RMW-free grid barrier: per-block flag lines + wave-parallel poll
//     (kills same-line atomic RMW/poll contention at the coherence point),
//     (2) A-prefetch depth 16, (3) fast LDS-staged setup kernel.
// ============================================================================

#define TSEQ  32
#define BATCH 2048
#define HDIM  512
#define GDIM  2048   // 4*H
#define NBLK  256
#define NTHR  512
#define DEPTH 16     // A-fragment prefetch pipeline depth (chunks of K=16)

typedef __bf16 bf16x8 __attribute__((ext_vector_type(8)));
typedef float  f32x16 __attribute__((ext_vector_type(16)));
typedef unsigned long long u64;

// ---- LDS layout (byte offsets), total 163584 <= 163840 (160 KiB) ----
#define BS_OFF     0          // Bs: w_hh slice [128 n][64 atoms x 16B], xor-swizzled (131072)
#define UNI_OFF    131072     // union: hP [128][33] f32 (16896) | h2s [128][16] f32 (8192)
#define H1_OFF     147968     // h1s  [128 m][24 bf16] stride 48 B (6144)
#define W1_OFF     154112     // W1fs [128 n][24 bf16]             (6144)
#define HPW_OFF    160256     // hpw1s [32 jj][16 q] bf16          (1024)
#define BIASF_OFF  161280     // bias_fs [128] f32                 (512)
#define LPS_OFF    161792     // lps [128][2] f32                  (1024)
#define PRM_OFF    162816     // folded params (~130 f32)          (768)
#define LDS_TOTAL  163584

// ---- workspace layout (bytes) ----
#define WS_W1F    0                        // [2048][16] f32 : se_w2 @ w_ih^T
#define WS_BIASF  131072                   // [2048]     f32
#define WS_FLAGS  139264                   // 256 flags x 128 B (32768)
#define WS_HBF    172032                   // 2 x [2048][512] bf16 (h, double buffered)
#define WS_PART   (WS_HBF + 2*2097152)     // 2 x [2048][16 j][8 qp] u64 (f32 pairs)

__device__ __forceinline__ unsigned short f2bf(float f) {   // RNE f32->bf16
  unsigned u = __float_as_uint(f);
  u += 0x7fffu + ((u >> 16) & 1u);
  return (unsigned short)(u >> 16);
}
__device__ __forceinline__ float bf2f(unsigned short b) {
  return __uint_as_float(((unsigned)b) << 16);
}
// relaxed agent-scope loads/stores -> plain global_load/store with sc0 sc1
// (device-coherent, bypass stale L1/L2, no cache-maintenance ops)
__device__ __forceinline__ u64 ld8(const void* p) {
  return __hip_atomic_load((const u64*)p, __ATOMIC_RELAXED, __HIP_MEMORY_SCOPE_AGENT);
}
__device__ __forceinline__ void st8(void* p, u64 v) {
  __hip_atomic_store((u64*)p, v, __ATOMIC_RELAXED, __HIP_MEMORY_SCOPE_AGENT);
}
__device__ __forceinline__ unsigned ld4(const unsigned* p) {
  return __hip_atomic_load(p, __ATOMIC_RELAXED, __HIP_MEMORY_SCOPE_AGENT);
}
__device__ __forceinline__ void st4(unsigned* p, unsigned v) {
  __hip_atomic_store(p, v, __ATOMIC_RELAXED, __HIP_MEMORY_SCOPE_AGENT);
}
__device__ __forceinline__ float lo32(u64 v) { return __uint_as_float((unsigned)v); }
__device__ __forceinline__ float hi32(u64 v) { return __uint_as_float((unsigned)(v >> 32)); }

// quad-perm broadcast: all 4 lanes of a quad receive lane (base+IMM)'s value
#define QB(x, imm) __uint_as_float((unsigned)__builtin_amdgcn_mov_dpp((int)__float_as_uint(x), imm, 0xF, 0xF, true))

struct KParams {
  const float *last_pos, *ch0, *w_hh;
  const float *se_w1, *se_b1, *se_g, *se_bt, *se_m, *se_v;
  const float *hp_w1, *hp_b1, *hp_g, *hp_bt, *hp_m, *hp_v, *hp_w2, *hp_b2;
  const float *W1f_g, *bias_f;
  unsigned short* h_bf;   // 2 buffers
  u64* part;              // 2 buffers
  unsigned* flags;        // 256 x 32 u32 (128B-spaced)
  float* out;
};

// ---------------------------------------------------------------------------
// Setup: W1f = se_w2 @ w_ih^T, fused bias, h0 -> bf16.  <<<2064, 128>>>
// blocks 0..2047: one gate-row each (LDS-staged w_ih row, 68-way dot split).
// blocks 2048..2063: h0 -> bf16 (128 rows each).
// ---------------------------------------------------------------------------
__global__ __launch_bounds__(128) void decoder_setup(
    const float* __restrict__ w_ih, const float* __restrict__ se_w2,
    const float* __restrict__ se_b2, const float* __restrict__ b_ih,
    const float* __restrict__ b_hh, const float* __restrict__ hh,
    float* __restrict__ W1f_g, float* __restrict__ bias_f,
    unsigned short* __restrict__ h_bf0) {
  int bid = blockIdx.x, tid = threadIdx.x;
  if (bid < GDIM) {
    __shared__ float wrow[512];
    __shared__ float psum[68];
    ((float4*)wrow)[tid] = ((const float4*)(w_ih + (size_t)bid * 512))[tid];
    __syncthreads();
    if (tid < 68) {
      int q = tid >> 2, quarter = tid & 3;
      const float* sw = (q < 16) ? (se_w2 + (size_t)q * 512) : se_b2;
      float s = 0.f;
      #pragma unroll 8
      for (int e = quarter * 128; e < quarter * 128 + 128; ++e)
        s += sw[e] * wrow[e];
      psum[tid] = s;
    }
    __syncthreads();
    if (tid < 17) {
      float s = psum[tid * 4] + psum[tid * 4 + 1] + psum[tid * 4 + 2] + psum[tid * 4 + 3];
      if (tid < 16) W1f_g[bid * 16 + tid] = s;
      else          bias_f[bid] = s + b_ih[bid] + b_hh[bid];
    }
  } else {
    int m = (bid - GDIM) * 128 + tid;       // hh is [1,B,H] flat
    const float* src = hh + (size_t)m * 512;
    unsigned short* dst = h_bf0 + (size_t)m * 512;
    for (int c = 0; c < 512; c += 8) {
      float4 f0 = ((const float4*)(src + c))[0];
      float4 f1 = ((const float4*)(src + c))[1];
      uint4 v;
      v.x = (unsigned)f2bf(f0.x) | ((unsigned)f2bf(f0.y) << 16);
      v.y = (unsigned)f2bf(f0.z) | ((unsigned)f2bf(f0.w) << 16);
      v.z = (unsigned)f2bf(f1.x) | ((unsigned)f2bf(f1.y) << 16);
      v.w = (unsigned)f2bf(f1.z) | ((unsigned)f2bf(f1.w) << 16);
      *(uint4*)(dst + c) = v;
    }
  }
}

// ---------------------------------------------------------------------------
// Persistent kernel. 256 blocks x 512 threads, 1 block/CU.
// Block (mt, nt): rows [mt*128, +128), hidden cols [nt*32, +32) x 4 gates,
// local n = 4*jj + gate (gate = 0:i 1:f 2:g 3:o).
// ---------------------------------------------------------------------------
__global__ __launch_bounds__(NTHR, 2) void decoder_persist(KParams p) {
  extern __shared__ char lds[];
  const int tid  = threadIdx.x;
  const int lane = tid & 63;
  const int wid  = tid >> 6;          // 0..7
  const int wm   = wid >> 1;          // 0..3 : rows wm*32..+32
  const int wn   = wid & 1;           // 0..1 : cols wn*64..+64 (2 acc tiles)
  const int mt   = blockIdx.x >> 4;
  const int nt   = blockIdx.x & 15;
  const int m0   = mt * 128;

  float* prm    = (float*)(lds + PRM_OFF);
  float* biasf  = (float*)(lds + BIASF_OFF);
  float* lps    = (float*)(lds + LPS_OFF);
  unsigned short* h1s   = (unsigned short*)(lds + H1_OFF);
  unsigned short* W1fs  = (unsigned short*)(lds + W1_OFF);
  unsigned short* hpw1s = (unsigned short*)(lds + HPW_OFF);

  // ---------------- one-time init ----------------
  if (tid < 16) {
    int q = tid;
    float sA = p.se_g[q] * rsqrtf(p.se_v[q] + 1e-5f);
    prm[q]      = sA;
    prm[16 + q] = (p.se_b1[q] - p.se_m[q]) * sA + p.se_bt[q];
    float hA = p.hp_g[q] * rsqrtf(p.hp_v[q] + 1e-5f);
    prm[32 + q] = hA;
    prm[48 + q] = (p.hp_b1[q] - p.hp_m[q]) * hA + p.hp_bt[q];
  }
  if (tid < 32) { prm[64 + tid] = p.se_w1[tid]; prm[96 + tid] = p.hp_w2[tid]; }
  if (tid < 2)  { prm[128 + tid] = p.hp_b2[tid]; }
  for (int n = tid; n < 128; n += NTHR) {
    int grow = (n & 3) * 512 + nt * 32 + (n >> 2);
    biasf[n] = p.bias_f[grow];
  }
  for (int id = tid; id < 2048; id += NTHR) {       // W1fs [128][16] bf16 (stride 24)
    int n = id >> 4, q = id & 15;
    int grow = (n & 3) * 512 + nt * 32 + (n >> 2);
    W1fs[n * 24 + q] = f2bf(p.W1f_g[grow * 16 + q]);
  }
  for (int id = tid; id < 512; id += NTHR) {        // hpw1s [32][16]
    int jj = id >> 4, q = id & 15;
    hpw1s[id] = f2bf(p.hp_w1[(nt * 32 + jj) * 16 + q]);
  }
  if (tid < 256) lps[tid] = p.last_pos[(size_t)m0 * 2 + tid];
  // Bs: w_hh slice -> bf16, atoms (n, ka) stored at n*64 + (ka ^ (n&7))
  for (int a = tid; a < 8192; a += NTHR) {
    int n = a >> 6, ka = a & 63;
    int grow = (n & 3) * 512 + nt * 32 + (n >> 2);
    const float* src = p.w_hh + (size_t)grow * 512 + ka * 8;
    uint4 v;
    v.x = (unsigned)f2bf(src[0]) | ((unsigned)f2bf(src[1]) << 16);
    v.y = (unsigned)f2bf(src[2]) | ((unsigned)f2bf(src[3]) << 16);
    v.z = (unsigned)f2bf(src[4]) | ((unsigned)f2bf(src[5]) << 16);
    v.w = (unsigned)f2bf(src[6]) | ((unsigned)f2bf(src[7]) << 16);
    *(uint4*)(lds + BS_OFF + ((size_t)(n * 64 + (ka ^ (n & 7)))) * 16) = v;
  }
  // c state in registers (valid on lanes with lane%4==0; 16 (row) x 2 (tile))
  float c_st[2][16];
  #pragma unroll
  for (int t2 = 0; t2 < 2; ++t2)
    #pragma unroll
    for (int r = 0; r < 16; ++r) c_st[t2][r] = 0.f;
  if ((lane & 3) == 0) {
    #pragma unroll
    for (int t2 = 0; t2 < 2; ++t2) {
      int n_loc = wn * 64 + t2 * 32 + (lane & 31);
      int jj = n_loc >> 2;
      #pragma unroll
      for (int r = 0; r < 16; ++r) {
        int row = (r & 3) + 8 * (r >> 2) + 4 * (lane >> 5) + wm * 32;
        c_st[t2][r] = p.ch0[(size_t)(m0 + row) * 512 + nt * 32 + jj];
      }
    }
  }
  __syncthreads();

  const int n0 = wn * 64 + (lane & 31);
  const int n1 = n0 + 32;
  const int gate = lane & 3;
  const int arow = m0 + wm * 32 + (lane & 31);
  const int asub = (lane >> 5) * 2;

  for (int t = 0; t <= TSEQ; ++t) {
    const int cur = t & 1, nxt = cur ^ 1, prv = cur ^ 1;   // (t-1)&1 == cur^1

    // ---------- prologue: lp_t = sigmoid(MLP2(h_t) + lp_{t-1}), traj[t-1] ----------
    if (t > 0) {
      float* h2s = (float*)(lds + UNI_OFF);                // [128][16]
      const u64* pin = p.part + (size_t)prv * BATCH * 128;
      #pragma unroll
      for (int u = 0; u < 2; ++u) {
        int id = u * NTHR + tid;                           // 128 m x 8 qp
        int m = id >> 3, qp = id & 7, q = qp * 2;
        const u64* base = pin + (size_t)(m0 + m) * 128 + qp;
        float s0 = 0.f, s1 = 0.f;
        #pragma unroll
        for (int j = 0; j < 16; ++j) {
          u64 x = ld8(base + j * 8);
          s0 += lo32(x); s1 += hi32(x);
        }
        float hv0 = s0 * prm[32 + q] + prm[48 + q];
        float hv1 = s1 * prm[33 + q] + prm[49 + q];
        h2s[m * 16 + q]     = fmaxf(hv0, 0.f);
        h2s[m * 16 + q + 1] = fmaxf(hv1, 0.f);
      }
      __syncthreads();
      if (tid < 256) {
        int m = tid >> 1, c = tid & 1;
        float a2 = prm[128 + c];
        #pragma unroll
        for (int q = 0; q < 16; ++q) a2 += h2s[m * 16 + q] * prm[96 + q * 2 + c];
        float lpv = 1.f / (1.f + __expf(-(a2 + lps[tid])));
        lps[tid] = lpv;
        if (nt == 0) p.out[((size_t)(t - 1) * BATCH + m0 + m) * 2 + c] = lpv;
      }
      __syncthreads();
    }
    if (t == TSEQ) break;

    // ---------- h1 = relu(affine(lp @ se_w1)) ----------
    #pragma unroll
    for (int u = 0; u < 4; ++u) {
      int id = u * NTHR + tid;
      int m = id >> 4, q = id & 15;
      float z = lps[m * 2] * prm[64 + q] + lps[m * 2 + 1] * prm[80 + q];
      h1s[m * 24 + q] = f2bf(fmaxf(z * prm[q] + prm[16 + q], 0.f));
    }
    __syncthreads();

    // ---------- acc init: xg = h1 @ W1f (K=16, one MFMA per tile) ----------
    f32x16 acc0, acc1;
    {
      f32x16 z;
      #pragma unroll
      for (int i = 0; i < 16; ++i) z[i] = 0.f;
      int mrow = wm * 32 + (lane & 31);
      bf16x8 av = *(const bf16x8*)((char*)h1s + mrow * 48 + (lane >> 5) * 16);
      bf16x8 b0 = *(const bf16x8*)((char*)W1fs + n0 * 48 + (lane >> 5) * 16);
      bf16x8 b1 = *(const bf16x8*)((char*)W1fs + n1 * 48 + (lane >> 5) * 16);
      acc0 = __builtin_amdgcn_mfma_f32_32x32x16_bf16(av, b0, z, 0, 0, 0);
      acc1 = __builtin_amdgcn_mfma_f32_32x32x16_bf16(av, b1, z, 0, 0, 0);
    }

    // ---------- main GEMM: gates += h_prev @ w_hh^T (A in registers) ----------
    {
      const u64* hq = (const u64*)(p.h_bf + (size_t)cur * BATCH * HDIM)
                      + (size_t)arow * 128 + asub;
      u64 pa[DEPTH], pb[DEPTH];
      #pragma unroll
      for (int c = 0; c < DEPTH; ++c) {
        pa[c] = ld8(hq + c * 4);
        pb[c] = ld8(hq + c * 4 + 1);
      }
      union AB { u64 q[2]; bf16x8 v; };
      #pragma unroll
      for (int c = 0; c < 32; ++c) {
        AB u;
        u.q[0] = pa[c & (DEPTH - 1)];
        u.q[1] = pb[c & (DEPTH - 1)];
        if (c + DEPTH < 32) {
          pa[c & (DEPTH - 1)] = ld8(hq + (c + DEPTH) * 4);
          pb[c & (DEPTH - 1)] = ld8(hq + (c + DEPTH) * 4 + 1);
        }
        int kal = c * 2 + (lane >> 5);
        bf16x8 b0 = *(const bf16x8*)(lds + BS_OFF + ((n0 << 6) + (kal ^ (n0 & 7))) * 16);
        bf16x8 b1 = *(const bf16x8*)(lds + BS_OFF + ((n1 << 6) + (kal ^ (n1 & 7))) * 16);
        acc0 = __builtin_amdgcn_mfma_f32_32x32x16_bf16(u.v, b0, acc0, 0, 0, 0);
        acc1 = __builtin_amdgcn_mfma_f32_32x32x16_bf16(u.v, b1, acc1, 0, 0, 0);
      }
    }

    // ---------- epilogue: LSTM cell update (quad-lane exchange via DPP) ----------
    float* hP = (float*)(lds + UNI_OFF);                   // [128][33]
    #pragma unroll
    for (int t2 = 0; t2 < 2; ++t2) {
      int n_loc = wn * 64 + t2 * 32 + (lane & 31);
      float bias = biasf[n_loc];
      int jj = n_loc >> 2;
      float act[16];
      const f32x16& A = (t2 == 0) ? acc0 : acc1;
      #pragma unroll
      for (int r = 0; r < 16; ++r) {
        float v = A[r] + bias;
        float vv = (gate == 2) ? 2.f * v : v;
        float sg = 1.f / (1.f + __expf(-vv));
        act[r] = (gate == 2) ? 2.f * sg - 1.f : sg;
      }
      #pragma unroll
      for (int r = 0; r < 16; ++r) {
        float iv = QB(act[r], 0x00);
        float fv = QB(act[r], 0x55);
        float gv = QB(act[r], 0xAA);
        float ov = QB(act[r], 0xFF);
        float cn = fv * c_st[t2][r] + iv * gv;
        c_st[t2][r] = cn;
        float th = 2.f / (1.f + __expf(-2.f * cn)) - 1.f;
        float hn = ov * th;
        if ((lane & 3) == 0) {
          int row = (r & 3) + 8 * (r >> 2) + 4 * (lane >> 5) + wm * 32;
          hP[row * 33 + jj] = hn;
        }
      }
    }
    __syncthreads();

    // ---------- write h (bf16, next buffer) + hp partial sums (sc1 stores) ----------
    unsigned short* hdst = p.h_bf + (size_t)nxt * BATCH * HDIM;
    #pragma unroll
    for (int u = 0; u < 2; ++u) {
      int id = u * NTHR + tid;                             // 128 m x 8 groups of 4 cols
      int m = id >> 3, grp = id & 7;
      u64 pk = (u64)f2bf(hP[m * 33 + grp * 4])
             | ((u64)f2bf(hP[m * 33 + grp * 4 + 1]) << 16)
             | ((u64)f2bf(hP[m * 33 + grp * 4 + 2]) << 32)
             | ((u64)f2bf(hP[m * 33 + grp * 4 + 3]) << 48);
      st8(hdst + (size_t)(m0 + m) * 512 + nt * 32 + grp * 4, pk);
    }
    u64* pdst = p.part + (size_t)cur * BATCH * 128;
    #pragma unroll
    for (int u = 0; u < 2; ++u) {
      int id = u * NTHR + tid;                             // 128 m x 8 qp
      int m = id >> 3, qp = id & 7, q = qp * 2;
      float s0 = 0.f, s1 = 0.f;
      #pragma unroll
      for (int jj = 0; jj < 32; ++jj) {
        float h = hP[m * 33 + jj];
        s0 += h * bf2f(hpw1s[jj * 16 + q]);
        s1 += h * bf2f(hpw1s[jj * 16 + q + 1]);
      }
      u64 pk = (u64)__float_as_uint(s0) | ((u64)__float_as_uint(s1) << 32);
      st8(pdst + (size_t)(m0 + m) * 128 + nt * 8 + qp, pk);
    }

    // ---------- grid barrier: per-block flag store + wave-parallel poll ----------
    // Data stores are sc0/sc1 write-through; vmcnt(0) drains them to the
    // coherence point before the flag store. NO atomic RMWs anywhere.
    __asm__ volatile("s_waitcnt vmcnt(0)" ::: "memory");
    __syncthreads();                                       // all waves drained
    if (tid == 0) st4(p.flags + (size_t)blockIdx.x * 32, (unsigned)(t + 1));
    if (wid == 0) {
      const unsigned tgt = (unsigned)(t + 1);
      const unsigned* fl = p.flags + (size_t)lane * 32;
      for (;;) {
        unsigned a0 = ld4(fl);
        unsigned a1 = ld4(fl + 64 * 32);
        unsigned a2 = ld4(fl + 128 * 32);
        unsigned a3 = ld4(fl + 192 * 32);
        unsigned mn = min(min(a0, a1), min(a2, a3));
        if (__all((int)(mn >= tgt))) break;
        __builtin_amdgcn_s_sleep(4);
      }
    }
    __syncthreads();
  }
}

// ---------------------------------------------------------------------------
extern "C" void kernel_launch(void* const* d_in, const int* in_sizes, int n_in,
                              void* d_out, int out_size, void* d_ws, size_t ws_size,
                              hipStream_t stream) {
  char* ws = (char*)d_ws;
  const float* last_pos = (const float*)d_in[0];
  const float* hh    = (const float*)d_in[1];
  const float* ch    = (const float*)d_in[2];
  const float* se_w1 = (const float*)d_in[3];
  const float* se_b1 = (const float*)d_in[4];
  const float* se_g  = (const float*)d_in[5];
  const float* se_bt = (const float*)d_in[6];
  const float* se_m  = (const float*)d_in[7];
  const float* se_v  = (const float*)d_in[8];
  const float* se_w2 = (const float*)d_in[9];
  const float* se_b2 = (const float*)d_in[10];
  const float* w_ih  = (const float*)d_in[11];
  const float* w_hh  = (const float*)d_in[12];
  const float* b_ih  = (const float*)d_in[13];
  const float* b_hh  = (const float*)d_in[14];
  const float* hp_w1 = (const float*)d_in[15];
  const float* hp_b1 = (const float*)d_in[16];
  const float* hp_g  = (const float*)d_in[17];
  const float* hp_bt = (const float*)d_in[18];
  const float* hp_m  = (const float*)d_in[19];
  const float* hp_v  = (const float*)d_in[20];
  const float* hp_w2 = (const float*)d_in[21];
  const float* hp_b2 = (const float*)d_in[22];

  float* W1f_g  = (float*)(ws + WS_W1F);
  float* bias_f = (float*)(ws + WS_BIASF);
  unsigned* flags = (unsigned*)(ws + WS_FLAGS);
  unsigned short* h_bf = (unsigned short*)(ws + WS_HBF);
  u64* part     = (u64*)(ws + WS_PART);

  hipMemsetAsync(ws + WS_FLAGS, 0, 32768, stream);
  decoder_setup<<<dim3(GDIM + 16), dim3(128), 0, stream>>>(
      w_ih, se_w2, se_b2, b_ih, b_hh, hh, W1f_g, bias_f, h_bf);

  hipFuncSetAttribute((const void*)decoder_persist,
                      hipFuncAttributeMaxDynamicSharedMemorySize, LDS_TOTAL);

  KParams kp;
  kp.last_pos = last_pos; kp.ch0 = ch; kp.w_hh = w_hh;
  kp.se_w1 = se_w1; kp.se_b1 = se_b1; kp.se_g = se_g; kp.se_bt = se_bt;
  kp.se_m = se_m; kp.se_v = se_v;
  kp.hp_w1 = hp_w1; kp.hp_b1 = hp_b1; kp.hp_g = hp_g; kp.hp_bt = hp_bt;
  kp.hp_m = hp_m; kp.hp_v = hp_v; kp.hp_w2 = hp_w2; kp.hp_b2 = hp_b2;
  kp.W1f_g = W1f_g; kp.bias_f = bias_f;
  kp.h_bf = h_bf; kp.part = part; kp.flags = flags; kp.out = (float*)d_out;

  void* args[] = { &kp };
  hipLaunchCooperativeKernel((void*)decoder_persist, dim3(NBLK), dim3(NTHR),
                             args, LDS_TOTAL, stream);
}

// Round 6
// 665.835 us; speedup vs baseline: 2.3598x; 1.8848x over previous
//
#include <hip/hip_runtime.h>

// ============================================================================
// Decoder_70437463654609: 32-step LSTM recurrence, B=2048 H=512 HID=16.
// R6: R5's coalesced layouts WITHOUT inline asm (suspected silent launch fail
// from pinned asm-output VGPRs). All cross-block traffic via 8B relaxed
// agent-scope atomics (sc0 sc1, compiler-tracked), consecutive lanes ->
// consecutive addresses:
//   - h exchanged in MFMA A-fragment atom layout (512B contiguous per wave ld8)
//   - partials bf16, j-major
//   - per-mt-group flags (16-block sync domains)
// ============================================================================

#define TSEQ  32
#define BATCH 2048
#define HDIM  512
#define GDIM  2048   // 4*H
#define NBLK  256
#define NTHR  512
#define DEPTH 16     // A-prefetch pipeline depth (K16 chunks)

typedef __bf16 bf16x8 __attribute__((ext_vector_type(8)));
typedef float  f32x16 __attribute__((ext_vector_type(16)));
typedef unsigned long long u64;

// ---- LDS layout (byte offsets), total 163,360 <= 163,840 ----
#define BS_OFF     0          // Bs: w_hh slice [128 n][64 k8 atoms x 16B], xor-swizzled (131072)
#define HP_OFF     131072     // hP bf16 [128 m][36] stride 72 B (9216)
#define UNI_OFF    140288     // h2s [128][16] f32 (8192)
#define H1_OFF     148480     // h1s  [128 m][24 bf16] stride 48 B (6144)
#define W1_OFF     154624     // W1fs [128 n][24 bf16]             (6144)
#define HPW_OFF    160768     // hpw1s [32 jj][16 q] bf16          (1024)
#define LPS_OFF    161792     // lps [128][2] f32                  (1024)
#define PRM_OFF    162816     // folded params (130 f32)           (544)
#define LDS_TOTAL  163360

// ---- workspace layout (bytes) ----
#define WS_W1F    0                        // [2048][16] f32 : se_w2 @ w_ih^T
#define WS_BIASF  131072                   // [2048] f32
#define WS_FLAGS  139264                   // 16 groups x 128 B
#define WS_HATOM  141312                   // 2 x (16 mt x 128 KB)  h atoms
#define WS_PART   (WS_HATOM + 2*2097152)   // 2 x (16 mt x 64 KB)   bf16 partials

__device__ __forceinline__ unsigned f2bf(float f) {   // RNE f32->bf16 (low 16)
  unsigned u = __float_as_uint(f);
  u += 0x7fffu + ((u >> 16) & 1u);
  return u >> 16;
}
__device__ __forceinline__ float bf2f(unsigned short b) {
  return __uint_as_float(((unsigned)b) << 16);
}
// relaxed agent-scope 8B/4B ops -> global_load/store ... sc0 sc1
// (device-coherent, no cache-wide maintenance, compiler-tracked waits)
__device__ __forceinline__ u64 ld8(const void* p) {
  return __hip_atomic_load((const u64*)p, __ATOMIC_RELAXED, __HIP_MEMORY_SCOPE_AGENT);
}
__device__ __forceinline__ void st8(void* p, u64 v) {
  __hip_atomic_store((u64*)p, v, __ATOMIC_RELAXED, __HIP_MEMORY_SCOPE_AGENT);
}
__device__ __forceinline__ unsigned ld4(const unsigned* p) {
  return __hip_atomic_load(p, __ATOMIC_RELAXED, __HIP_MEMORY_SCOPE_AGENT);
}
__device__ __forceinline__ void st4(unsigned* p, unsigned v) {
  __hip_atomic_store(p, v, __ATOMIC_RELAXED, __HIP_MEMORY_SCOPE_AGENT);
}
// quad-perm broadcast
#define QB(x, imm) __uint_as_float((unsigned)__builtin_amdgcn_mov_dpp((int)__float_as_uint(x), imm, 0xF, 0xF, true))

struct KParams {
  const float *last_pos, *ch0, *w_hh;
  const float *se_w1, *se_b1, *se_g, *se_bt, *se_m, *se_v;
  const float *hp_w1, *hp_b1, *hp_g, *hp_bt, *hp_m, *hp_v, *hp_w2, *hp_b2;
  const float *W1f_g, *bias_f;
  char* hatom;            // 2 parities x 2 MB
  char* part;             // 2 parities x 1 MB
  unsigned* flags;        // 16 x 32 u32
  float* out;
};

// ---------------------------------------------------------------------------
// Setup: W1f = se_w2 @ w_ih^T, fused bias, h0 -> atom layout.  <<<2064,128>>>
// Atom map (per mt tile): linear a = (k8>>1)*256 + (m>>5)*64 + (k8&1)*32 + (m&31)
// ---------------------------------------------------------------------------
__global__ __launch_bounds__(128) void decoder_setup(
    const float* __restrict__ w_ih, const float* __restrict__ se_w2,
    const float* __restrict__ se_b2, const float* __restrict__ b_ih,
    const float* __restrict__ b_hh, const float* __restrict__ hh,
    float* __restrict__ W1f_g, float* __restrict__ bias_f,
    char* __restrict__ hatom) {
  int bid = blockIdx.x, tid = threadIdx.x;
  if (bid < GDIM) {
    __shared__ float wrow[512];
    __shared__ float psum[68];
    ((float4*)wrow)[tid] = ((const float4*)(w_ih + (size_t)bid * 512))[tid];
    __syncthreads();
    if (tid < 68) {
      int q = tid >> 2, quarter = tid & 3;
      const float* sw = (q < 16) ? (se_w2 + (size_t)q * 512) : se_b2;
      float s = 0.f;
      #pragma unroll 8
      for (int e = quarter * 128; e < quarter * 128 + 128; ++e)
        s += sw[e] * wrow[e];
      psum[tid] = s;
    }
    __syncthreads();
    if (tid < 17) {
      float s = psum[tid * 4] + psum[tid * 4 + 1] + psum[tid * 4 + 2] + psum[tid * 4 + 3];
      if (tid < 16) W1f_g[bid * 16 + tid] = s;
      else          bias_f[bid] = s + b_ih[bid] + b_hh[bid];
    }
  } else {
    // h0 atoms -> parity 1.  a = slot*64+lane; m=(slot&3)*32+(lane&31);
    // k8=(slot>>2)*2+(lane>>5)  (satisfies the atom map above)
    int mt = bid - GDIM;
    const float* src = hh + (size_t)mt * 128 * 512;
    char* dst = hatom + 2097152 + (size_t)mt * 131072;
    for (int a = tid; a < 8192; a += 128) {
      int lane = a & 63, slot = a >> 6;
      int m = (slot & 3) * 32 + (lane & 31);
      int k8 = (slot >> 2) * 2 + (lane >> 5);
      const float* s8 = src + (size_t)m * 512 + k8 * 8;
      uint4 v;
      v.x = f2bf(s8[0]) | (f2bf(s8[1]) << 16);
      v.y = f2bf(s8[2]) | (f2bf(s8[3]) << 16);
      v.z = f2bf(s8[4]) | (f2bf(s8[5]) << 16);
      v.w = f2bf(s8[6]) | (f2bf(s8[7]) << 16);
      *(uint4*)(dst + (size_t)a * 16) = v;
    }
  }
}

// ---------------------------------------------------------------------------
// Persistent kernel. 256 blocks x 512 threads, 1 block/CU.
// Block (mt, nt): rows [mt*128,+128), local n = 4*jj + gate.
// ---------------------------------------------------------------------------
__global__ __launch_bounds__(NTHR, 2) void decoder_persist(KParams p) {
  extern __shared__ char lds[];
  const int tid  = threadIdx.x;
  const int lane = tid & 63;
  const int wid  = tid >> 6;
  const int wm   = wid >> 1;
  const int wn   = wid & 1;
  const int mt   = blockIdx.x >> 4;
  const int nt   = blockIdx.x & 15;
  const int m0   = mt * 128;

  float* prm    = (float*)(lds + PRM_OFF);
  float* lps    = (float*)(lds + LPS_OFF);
  float* h2s    = (float*)(lds + UNI_OFF);
  unsigned short* hPsh  = (unsigned short*)(lds + HP_OFF);
  unsigned short* h1s   = (unsigned short*)(lds + H1_OFF);
  unsigned short* W1fs  = (unsigned short*)(lds + W1_OFF);
  unsigned short* hpw1s = (unsigned short*)(lds + HPW_OFF);

  // ---------------- one-time init ----------------
  if (tid < 16) {
    int q = tid;
    float sA = p.se_g[q] * rsqrtf(p.se_v[q] + 1e-5f);
    prm[q]      = sA;
    prm[16 + q] = (p.se_b1[q] - p.se_m[q]) * sA + p.se_bt[q];
    float hA = p.hp_g[q] * rsqrtf(p.hp_v[q] + 1e-5f);
    prm[32 + q] = hA;
    prm[48 + q] = (p.hp_b1[q] - p.hp_m[q]) * hA + p.hp_bt[q];
  }
  if (tid < 32) { prm[64 + tid] = p.se_w1[tid]; prm[96 + tid] = p.hp_w2[tid]; }
  if (tid < 2)  { prm[128 + tid] = p.hp_b2[tid]; }
  for (int id = tid; id < 2048; id += NTHR) {       // W1fs [128][16] (stride 24)
    int n = id >> 4, q = id & 15;
    int grow = (n & 3) * 512 + nt * 32 + (n >> 2);
    W1fs[n * 24 + q] = f2bf(p.W1f_g[grow * 16 + q]);
  }
  for (int id = tid; id < 512; id += NTHR) {        // hpw1s [32][16]
    int jj = id >> 4, q = id & 15;
    hpw1s[id] = f2bf(p.hp_w1[(nt * 32 + jj) * 16 + q]);
  }
  if (tid < 256) lps[tid] = p.last_pos[(size_t)m0 * 2 + tid];
  float biasr[2];
  #pragma unroll
  for (int t2 = 0; t2 < 2; ++t2) {
    int n = wn * 64 + t2 * 32 + (lane & 31);
    int grow = (n & 3) * 512 + nt * 32 + (n >> 2);
    biasr[t2] = p.bias_f[grow];
  }
  // Bs: w_hh slice -> bf16 atoms (n, k8) at n*64 + (k8 ^ (n&7))
  for (int a = tid; a < 8192; a += NTHR) {
    int n = a >> 6, ka = a & 63;
    int grow = (n & 3) * 512 + nt * 32 + (n >> 2);
    const float* src = p.w_hh + (size_t)grow * 512 + ka * 8;
    uint4 v;
    v.x = f2bf(src[0]) | (f2bf(src[1]) << 16);
    v.y = f2bf(src[2]) | (f2bf(src[3]) << 16);
    v.z = f2bf(src[4]) | (f2bf(src[5]) << 16);
    v.w = f2bf(src[6]) | (f2bf(src[7]) << 16);
    *(uint4*)(lds + BS_OFF + ((size_t)(n * 64 + (ka ^ (n & 7)))) * 16) = v;
  }
  // c state (lanes with lane%4==0), 16 rows x 2 tiles
  float c_st[2][16];
  #pragma unroll
  for (int t2 = 0; t2 < 2; ++t2)
    #pragma unroll
    for (int r = 0; r < 16; ++r) c_st[t2][r] = 0.f;
  if ((lane & 3) == 0) {
    #pragma unroll
    for (int t2 = 0; t2 < 2; ++t2) {
      int n_loc = wn * 64 + t2 * 32 + (lane & 31);
      int jj = n_loc >> 2;
      #pragma unroll
      for (int r = 0; r < 16; ++r) {
        int row = (r & 3) + 8 * (r >> 2) + 4 * (lane >> 5) + wm * 32;
        c_st[t2][r] = p.ch0[(size_t)(m0 + row) * 512 + nt * 32 + jj];
      }
    }
  }
  __syncthreads();

  const int n0 = wn * 64 + (lane & 31);
  const int n1 = n0 + 32;
  const int gate = lane & 3;
  const int khalf = lane >> 5;
  // h-atom producer map: pj = ((tid>>8)<<1)|((tid>>5)&1); pm = ((tid>>6)&3)*32+(tid&31)
  const int pj = ((tid >> 8) << 1) | ((tid >> 5) & 1);
  const int pm = ((tid >> 6) & 3) * 32 + (tid & 31);

  for (int t = 0; t <= TSEQ; ++t) {
    // ---------- wait group flags >= t; prologue from partials_{t-1} ----------
    if (t > 0) {
      if (wid == 0) {
        const unsigned* fl = p.flags + mt * 32 + (lane & 15);
        while (!__all((int)(ld4(fl) >= (unsigned)t)))
          __builtin_amdgcn_s_sleep(2);
      }
      __syncthreads();
      if (tid < 256) {
        const u64* pbase = (const u64*)(p.part + (size_t)((t + 1) & 1) * 1048576
                                        + mt * 65536);
        u64 pr0[16], pr1[16];
        #pragma unroll
        for (int j = 0; j < 16; ++j) {
          pr0[j] = ld8(pbase + (j * 256 + tid) * 2);
          pr1[j] = ld8(pbase + (j * 256 + tid) * 2 + 1);
        }
        int m = tid >> 1, oct = tid & 1;
        float s[8];
        #pragma unroll
        for (int i = 0; i < 8; ++i) s[i] = 0.f;
        #pragma unroll
        for (int j = 0; j < 16; ++j) {
          u64 x = pr0[j], y = pr1[j];
          s[0] += bf2f((unsigned short)x);         s[1] += bf2f((unsigned short)(x >> 16));
          s[2] += bf2f((unsigned short)(x >> 32)); s[3] += bf2f((unsigned short)(x >> 48));
          s[4] += bf2f((unsigned short)y);         s[5] += bf2f((unsigned short)(y >> 16));
          s[6] += bf2f((unsigned short)(y >> 32)); s[7] += bf2f((unsigned short)(y >> 48));
        }
        #pragma unroll
        for (int i = 0; i < 8; ++i) {
          int q = oct * 8 + i;
          h2s[m * 16 + q] = fmaxf(s[i] * prm[32 + q] + prm[48 + q], 0.f);
        }
      }
      __syncthreads();
      if (tid < 256) {
        int m = tid >> 1, c = tid & 1;
        float a2 = prm[128 + c];
        #pragma unroll
        for (int q = 0; q < 16; ++q) a2 += h2s[m * 16 + q] * prm[96 + q * 2 + c];
        float lpv = 1.f / (1.f + __expf(-(a2 + lps[tid])));
        lps[tid] = lpv;
        if (nt == 0) p.out[((size_t)(t - 1) * BATCH + m0 + m) * 2 + c] = lpv;
      }
      __syncthreads();
    }
    if (t == TSEQ) break;

    // ---------- h1 = relu(affine(lp @ se_w1)) ----------
    #pragma unroll
    for (int u = 0; u < 4; ++u) {
      int id = u * NTHR + tid;
      int m = id >> 4, q = id & 15;
      float z = lps[m * 2] * prm[64 + q] + lps[m * 2 + 1] * prm[80 + q];
      h1s[m * 24 + q] = f2bf(fmaxf(z * prm[q] + prm[16 + q], 0.f));
    }
    __syncthreads();

    // ---------- acc init: xg = h1 @ W1f ----------
    f32x16 acc0, acc1;
    {
      f32x16 z;
      #pragma unroll
      for (int i = 0; i < 16; ++i) z[i] = 0.f;
      int mrow = wm * 32 + (lane & 31);
      bf16x8 av = *(const bf16x8*)((char*)h1s + mrow * 48 + khalf * 16);
      bf16x8 b0 = *(const bf16x8*)((char*)W1fs + n0 * 48 + khalf * 16);
      bf16x8 b1 = *(const bf16x8*)((char*)W1fs + n1 * 48 + khalf * 16);
      acc0 = __builtin_amdgcn_mfma_f32_32x32x16_bf16(av, b0, z, 0, 0, 0);
      acc1 = __builtin_amdgcn_mfma_f32_32x32x16_bf16(av, b1, z, 0, 0, 0);
    }

    // ---------- main GEMM: coalesced atom stream (8B/lane, consecutive) ----------
    {
      // atom a = c*256 + wm*64 + lane  ->  u64 idx = c*512 + (wm*64+lane)*2
      const u64* aq = (const u64*)(p.hatom + (size_t)((t + 1) & 1) * 2097152
                                   + mt * 131072) + (wm * 64 + lane) * 2;
      u64 pa[DEPTH], pb[DEPTH];
      #pragma unroll
      for (int c = 0; c < DEPTH; ++c) {
        pa[c] = ld8(aq + c * 512);
        pb[c] = ld8(aq + c * 512 + 1);
      }
      union AB { u64 q[2]; bf16x8 v; };
      #pragma unroll
      for (int c = 0; c < 32; ++c) {
        AB u;
        u.q[0] = pa[c & (DEPTH - 1)];
        u.q[1] = pb[c & (DEPTH - 1)];
        if (c + DEPTH < 32) {
          pa[c & (DEPTH - 1)] = ld8(aq + (c + DEPTH) * 512);
          pb[c & (DEPTH - 1)] = ld8(aq + (c + DEPTH) * 512 + 1);
        }
        int kal = c * 2 + khalf;
        bf16x8 b0 = *(const bf16x8*)(lds + BS_OFF + (((n0 << 6) + (kal ^ (n0 & 7))) << 4));
        bf16x8 b1 = *(const bf16x8*)(lds + BS_OFF + (((n1 << 6) + (kal ^ (n1 & 7))) << 4));
        acc0 = __builtin_amdgcn_mfma_f32_32x32x16_bf16(u.v, b0, acc0, 0, 0, 0);
        acc1 = __builtin_amdgcn_mfma_f32_32x32x16_bf16(u.v, b1, acc1, 0, 0, 0);
      }
    }

    // ---------- epilogue: LSTM cell update ----------
    #pragma unroll
    for (int t2 = 0; t2 < 2; ++t2) {
      int n_loc = wn * 64 + t2 * 32 + (lane & 31);
      float bias = biasr[t2];
      int jj = n_loc >> 2;
      float act[16];
      const f32x16& A = (t2 == 0) ? acc0 : acc1;
      #pragma unroll
      for (int r = 0; r < 16; ++r) {
        float v = A[r] + bias;
        float vv = (gate == 2) ? 2.f * v : v;
        float sg = 1.f / (1.f + __expf(-vv));
        act[r] = (gate == 2) ? 2.f * sg - 1.f : sg;
      }
      #pragma unroll
      for (int r = 0; r < 16; ++r) {
        float iv = QB(act[r], 0x00);
        float fv = QB(act[r], 0x55);
        float gv = QB(act[r], 0xAA);
        float ov = QB(act[r], 0xFF);
        float cn = fv * c_st[t2][r] + iv * gv;
        c_st[t2][r] = cn;
        float th = 2.f / (1.f + __expf(-2.f * cn)) - 1.f;
        float hn = ov * th;
        if ((lane & 3) == 0) {
          int row = (r & 3) + 8 * (r >> 2) + 4 * (lane >> 5) + wm * 32;
          hPsh[row * 36 + jj] = (unsigned short)f2bf(hn);
        }
      }
    }
    __syncthreads();

    // ---------- coalesced h-atom + bf16 partial stores ----------
    {
      const u64* hp8 = (const u64*)(lds + HP_OFF + pm * 72 + pj * 16);
      u64* hdst = (u64*)(p.hatom + (size_t)(t & 1) * 2097152 + mt * 131072);
      st8(hdst + (512 * nt + tid) * 2,     hp8[0]);
      st8(hdst + (512 * nt + tid) * 2 + 1, hp8[1]);
    }
    if (tid < 256) {
      int m2 = tid >> 1, oct = tid & 1;
      float s[8];
      #pragma unroll
      for (int i = 0; i < 8; ++i) s[i] = 0.f;
      #pragma unroll
      for (int jj = 0; jj < 32; ++jj) {
        float h = bf2f(hPsh[m2 * 36 + jj]);
        #pragma unroll
        for (int i = 0; i < 8; ++i)
          s[i] += h * bf2f(hpw1s[jj * 16 + oct * 8 + i]);
      }
      u64 lo = (u64)f2bf(s[0]) | ((u64)f2bf(s[1]) << 16)
             | ((u64)f2bf(s[2]) << 32) | ((u64)f2bf(s[3]) << 48);
      u64 hi = (u64)f2bf(s[4]) | ((u64)f2bf(s[5]) << 16)
             | ((u64)f2bf(s[6]) << 32) | ((u64)f2bf(s[7]) << 48);
      u64* pdst = (u64*)(p.part + (size_t)(t & 1) * 1048576 + mt * 65536);
      st8(pdst + (nt * 256 + tid) * 2,     lo);
      st8(pdst + (nt * 256 + tid) * 2 + 1, hi);
    }
    __syncthreads();   // implicit s_waitcnt vmcnt(0) drains the sc1 stores
    if (tid == 0) st4(p.flags + mt * 32 + nt, (unsigned)(t + 1));
  }
}

// ---------------------------------------------------------------------------
extern "C" void kernel_launch(void* const* d_in, const int* in_sizes, int n_in,
                              void* d_out, int out_size, void* d_ws, size_t ws_size,
                              hipStream_t stream) {
  char* ws = (char*)d_ws;
  const float* last_pos = (const float*)d_in[0];
  const float* hh    = (const float*)d_in[1];
  const float* ch    = (const float*)d_in[2];
  const float* se_w1 = (const float*)d_in[3];
  const float* se_b1 = (const float*)d_in[4];
  const float* se_g  = (const float*)d_in[5];
  const float* se_bt = (const float*)d_in[6];
  const float* se_m  = (const float*)d_in[7];
  const float* se_v  = (const float*)d_in[8];
  const float* se_w2 = (const float*)d_in[9];
  const float* se_b2 = (const float*)d_in[10];
  const float* w_ih  = (const float*)d_in[11];
  const float* w_hh  = (const float*)d_in[12];
  const float* b_ih  = (const float*)d_in[13];
  const float* b_hh  = (const float*)d_in[14];
  const float* hp_w1 = (const float*)d_in[15];
  const float* hp_b1 = (const float*)d_in[16];
  const float* hp_g  = (const float*)d_in[17];
  const float* hp_bt = (const float*)d_in[18];
  const float* hp_m  = (const float*)d_in[19];
  const float* hp_v  = (const float*)d_in[20];
  const float* hp_w2 = (const float*)d_in[21];
  const float* hp_b2 = (const float*)d_in[22];

  float* W1f_g  = (float*)(ws + WS_W1F);
  float* bias_f = (float*)(ws + WS_BIASF);
  unsigned* flags = (unsigned*)(ws + WS_FLAGS);
  char* hatom   = ws + WS_HATOM;
  char* part    = ws + WS_PART;

  (void)hipMemsetAsync(ws + WS_FLAGS, 0, 2048, stream);
  decoder_setup<<<dim3(GDIM + 16), dim3(128), 0, stream>>>(
      w_ih, se_w2, se_b2, b_ih, b_hh, hh, W1f_g, bias_f, hatom);

  (void)hipFuncSetAttribute((const void*)decoder_persist,
                            hipFuncAttributeMaxDynamicSharedMemorySize, LDS_TOTAL);

  KParams kp;
  kp.last_pos = last_pos; kp.ch0 = ch; kp.w_hh = w_hh;
  kp.se_w1 = se_w1; kp.se_b1 = se_b1; kp.se_g = se_g; kp.se_bt = se_bt;
  kp.se_m = se_m; kp.se_v = se_v;
  kp.hp_w1 = hp_w1; kp.hp_b1 = hp_b1; kp.hp_g = hp_g; kp.hp_bt = hp_bt;
  kp.hp_m = hp_m; kp.hp_v = hp_v; kp.hp_w2 = hp_w2; kp.hp_b2 = hp_b2;
  kp.W1f_g = W1f_g; kp.bias_f = bias_f;
  kp.hatom = hatom; kp.part = part; kp.flags = flags; kp.out = (float*)d_out;

  void* args[] = { &kp };
  (void)hipLaunchCooperativeKernel((void*)decoder_persist, dim3(NBLK), dim3(NTHR),
                                   args, LDS_TOTAL, stream);
}

// Round 7
// 652.843 us; speedup vs baseline: 2.4068x; 1.0199x over previous
//
#include <hip/hip_runtime.h>

// ============================================================================
// Decoder_70437463654609: 32-step LSTM recurrence, B=2048 H=512 HID=16.
// R7: hp-MLP fused into the GEMM K-loop (P = h@hp_w1 via a 3rd MFMA on wn==0
// waves) -> lp computed block-locally, NO cross-block partials. xg = h1@W1f
// added as the LAST MFMA so the GEMM starts immediately after the flag wait.
// Cross-block exchange = h atoms only (coalesced 8B/lane sc0sc1, R6-proven).
// Fast parallel setup kernel (320x256).
// ============================================================================

#define TSEQ  32
#define BATCH 2048
#define HDIM  512
#define GDIM  2048   // 4*H
#define NBLK  256
#define NTHR  512
#define DEPTH 16     // A-prefetch pipeline depth (K16 chunks)

typedef __bf16 bf16x8 __attribute__((ext_vector_type(8)));
typedef float  f32x16 __attribute__((ext_vector_type(16)));
typedef unsigned long long u64;

// ---- LDS layout (byte offsets), total 163,360 <= 163,840 ----
#define BS_OFF     0          // Bs: w_hh slice [128 n][64 k8 atoms x 16B], swz (131072)
#define HPW_OFF    131072     // hp_w1 atoms [16 n][64 k8 x 16B], swz (16384)
#define UNI_OFF    147456     // union: h2s [128][20] f32 (10240) | hP bf16 [128][36] (9216)
#define H1_OFF     157696     // h1s [128 m][16 bf16] stride 32 B (4096)
#define LPS_OFF    161792     // lps [128][2] f32 (1024)
#define PRM_OFF    162816     // folded params (130 f32) (544)
#define LDS_TOTAL  163360

// ---- workspace layout (bytes) ----
#define WS_W1F    0                        // [2048][16] f32 : se_w2 @ w_ih^T
#define WS_BIASF  131072                   // [2048] f32
#define WS_FLAGS  139264                   // 16 groups x 128 B
#define WS_HATOM  141312                   // 2 x (16 mt x 128 KB)  h atoms

__device__ __forceinline__ unsigned f2bf(float f) {   // RNE f32->bf16 (low 16)
  unsigned u = __float_as_uint(f);
  u += 0x7fffu + ((u >> 16) & 1u);
  return u >> 16;
}
__device__ __forceinline__ float bf2f(unsigned short b) {
  return __uint_as_float(((unsigned)b) << 16);
}
// relaxed agent-scope ops -> global_load/store ... sc0 sc1 (device-coherent)
__device__ __forceinline__ u64 ld8(const void* p) {
  return __hip_atomic_load((const u64*)p, __ATOMIC_RELAXED, __HIP_MEMORY_SCOPE_AGENT);
}
__device__ __forceinline__ void st8(void* p, u64 v) {
  __hip_atomic_store((u64*)p, v, __ATOMIC_RELAXED, __HIP_MEMORY_SCOPE_AGENT);
}
__device__ __forceinline__ unsigned ld4(const unsigned* p) {
  return __hip_atomic_load(p, __ATOMIC_RELAXED, __HIP_MEMORY_SCOPE_AGENT);
}
__device__ __forceinline__ void st4(unsigned* p, unsigned v) {
  __hip_atomic_store(p, v, __ATOMIC_RELAXED, __HIP_MEMORY_SCOPE_AGENT);
}
// quad-perm broadcast
#define QB(x, imm) __uint_as_float((unsigned)__builtin_amdgcn_mov_dpp((int)__float_as_uint(x), imm, 0xF, 0xF, true))

struct KParams {
  const float *last_pos, *ch0, *w_hh;
  const float *se_w1, *se_b1, *se_g, *se_bt, *se_m, *se_v;
  const float *hp_w1, *hp_b1, *hp_g, *hp_bt, *hp_m, *hp_v, *hp_w2, *hp_b2;
  const float *W1f_g, *bias_f;
  char* hatom;            // 2 parities x 2 MB
  unsigned* flags;        // 16 x 32 u32
  float* out;
};

// ---------------------------------------------------------------------------
// Setup <<<320, 256>>>: blocks 0..255: W1f/bias (8 gate-rows each, LDS-staged,
// fully parallel dots). blocks 256..319: h0 -> atom layout (parity 1).
// ---------------------------------------------------------------------------
__global__ __launch_bounds__(256) void decoder_setup(
    const float* __restrict__ w_ih, const float* __restrict__ se_w2,
    const float* __restrict__ se_b2, const float* __restrict__ b_ih,
    const float* __restrict__ b_hh, const float* __restrict__ hh,
    float* __restrict__ W1f_g, float* __restrict__ bias_f,
    char* __restrict__ hatom) {
  int bid = blockIdx.x, tid = threadIdx.x;
  if (bid < 256) {
    __shared__ float wrow[8 * 512];
    __shared__ float ps[256];
    __shared__ float psB[128];
    int r0 = bid * 8;
    #pragma unroll
    for (int i = 0; i < 4; ++i) {
      int idx = i * 256 + tid;
      ((float4*)wrow)[idx] = ((const float4*)(w_ih + (size_t)r0 * 512))[idx];
    }
    __syncthreads();
    {
      int r = tid >> 5, q = (tid >> 1) & 15, half = tid & 1;
      const float* sw = se_w2 + (size_t)q * 512 + half * 256;
      const float* wr = wrow + r * 512 + half * 256;
      float s = 0.f;
      #pragma unroll 8
      for (int e = 0; e < 256; ++e) s += sw[e] * wr[e];
      ps[tid] = s;
    }
    if (tid < 128) {
      int r = tid >> 4, seg = tid & 15;
      const float* wr = wrow + r * 512 + seg * 32;
      const float* sb = se_b2 + seg * 32;
      float s = 0.f;
      #pragma unroll
      for (int e = 0; e < 32; ++e) s += sb[e] * wr[e];
      psB[tid] = s;
    }
    __syncthreads();
    if (tid < 128) {
      int r = tid >> 4, q = tid & 15;
      W1f_g[(r0 + r) * 16 + q] = ps[r * 32 + q * 2] + ps[r * 32 + q * 2 + 1];
    } else if (tid < 136) {
      int r = tid - 128;
      float s = 0.f;
      #pragma unroll
      for (int i = 0; i < 16; ++i) s += psB[r * 16 + i];
      bias_f[r0 + r] = s + b_ih[r0 + r] + b_hh[r0 + r];
    }
  } else {
    int bb = bid - 256;
    for (int u = 0; u < 8; ++u) {
      int aidx = bb * 2048 + u * 256 + tid;     // 131072 atoms total
      int mtl = aidx >> 13, a = aidx & 8191;
      int lane = a & 63, slot = a >> 6;
      int m = (slot & 3) * 32 + (lane & 31);
      int k8 = (slot >> 2) * 2 + (lane >> 5);
      const float* s8 = hh + (size_t)mtl * 65536 + (size_t)m * 512 + k8 * 8;
      uint4 v;
      v.x = f2bf(s8[0]) | (f2bf(s8[1]) << 16);
      v.y = f2bf(s8[2]) | (f2bf(s8[3]) << 16);
      v.z = f2bf(s8[4]) | (f2bf(s8[5]) << 16);
      v.w = f2bf(s8[6]) | (f2bf(s8[7]) << 16);
      *(uint4*)(hatom + 2097152 + (size_t)mtl * 131072 + (size_t)a * 16) = v;
    }
  }
}

// ---------------------------------------------------------------------------
// Persistent kernel. 256 blocks x 512 threads, 1 block/CU.
// Block (mt, nt): rows [mt*128,+128), local n = 4*jj + gate.
// ---------------------------------------------------------------------------
__global__ __launch_bounds__(NTHR, 2) void decoder_persist(KParams p) {
  extern __shared__ char lds[];
  const int tid  = threadIdx.x;
  const int lane = tid & 63;
  const int wid  = tid >> 6;
  const int wm   = wid >> 1;
  const int wn   = wid & 1;
  const int mt   = blockIdx.x >> 4;
  const int nt   = blockIdx.x & 15;
  const int m0   = mt * 128;

  float* prm = (float*)(lds + PRM_OFF);
  float* lps = (float*)(lds + LPS_OFF);
  float* h2s = (float*)(lds + UNI_OFF);                   // stride 20 f32
  unsigned short* hPsh = (unsigned short*)(lds + UNI_OFF); // stride 36 u16
  unsigned short* h1s  = (unsigned short*)(lds + H1_OFF);  // stride 16 u16

  // ---------------- one-time init ----------------
  if (tid < 16) {
    int q = tid;
    float sA = p.se_g[q] * rsqrtf(p.se_v[q] + 1e-5f);
    prm[q]      = sA;
    prm[16 + q] = (p.se_b1[q] - p.se_m[q]) * sA + p.se_bt[q];
    float hA = p.hp_g[q] * rsqrtf(p.hp_v[q] + 1e-5f);
    prm[32 + q] = hA;
    prm[48 + q] = (p.hp_b1[q] - p.hp_m[q]) * hA + p.hp_bt[q];
  }
  if (tid < 32) { prm[64 + tid] = p.se_w1[tid]; prm[96 + tid] = p.hp_w2[tid]; }
  if (tid < 2)  { prm[128 + tid] = p.hp_b2[tid]; }
  if (tid < 256) lps[tid] = p.last_pos[(size_t)m0 * 2 + tid];
  float biasr[2];
  #pragma unroll
  for (int t2 = 0; t2 < 2; ++t2) {
    int n = wn * 64 + t2 * 32 + (lane & 31);
    int grow = (n & 3) * 512 + nt * 32 + (n >> 2);
    biasr[t2] = p.bias_f[grow];
  }
  // Bs: w_hh slice -> bf16 atoms (n, k8) at n*64 + (k8 ^ (n&7))
  for (int a = tid; a < 8192; a += NTHR) {
    int n = a >> 6, ka = a & 63;
    int grow = (n & 3) * 512 + nt * 32 + (n >> 2);
    const float* src = p.w_hh + (size_t)grow * 512 + ka * 8;
    uint4 v;
    v.x = f2bf(src[0]) | (f2bf(src[1]) << 16);
    v.y = f2bf(src[2]) | (f2bf(src[3]) << 16);
    v.z = f2bf(src[4]) | (f2bf(src[5]) << 16);
    v.w = f2bf(src[6]) | (f2bf(src[7]) << 16);
    *(uint4*)(lds + BS_OFF + ((size_t)(n * 64 + (ka ^ (n & 7)))) * 16) = v;
  }
  // hp_w1 atoms: atom (n<16, k8) = hp_w1[k8*8+j][n], j=0..7 (stride 16 floats)
  for (int a = tid; a < 1024; a += NTHR) {
    int n = a >> 6, k8 = a & 63;
    const float* src = p.hp_w1 + (size_t)(k8 * 8) * 16 + n;
    uint4 v;
    v.x = f2bf(src[0])   | (f2bf(src[16]) << 16);
    v.y = f2bf(src[32])  | (f2bf(src[48]) << 16);
    v.z = f2bf(src[64])  | (f2bf(src[80]) << 16);
    v.w = f2bf(src[96])  | (f2bf(src[112]) << 16);
    *(uint4*)(lds + HPW_OFF + ((size_t)(n * 64 + (k8 ^ (n & 7)))) * 16) = v;
  }
  // c state (lanes with lane%4==0), 16 rows x 2 tiles
  float c_st[2][16];
  #pragma unroll
  for (int t2 = 0; t2 < 2; ++t2)
    #pragma unroll
    for (int r = 0; r < 16; ++r) c_st[t2][r] = 0.f;
  if ((lane & 3) == 0) {
    #pragma unroll
    for (int t2 = 0; t2 < 2; ++t2) {
      int n_loc = wn * 64 + t2 * 32 + (lane & 31);
      int jj = n_loc >> 2;
      #pragma unroll
      for (int r = 0; r < 16; ++r) {
        int row = (r & 3) + 8 * (r >> 2) + 4 * (lane >> 5) + wm * 32;
        c_st[t2][r] = p.ch0[(size_t)(m0 + row) * 512 + nt * 32 + jj];
      }
    }
  }
  const int n0 = wn * 64 + (lane & 31);
  const int n1 = n0 + 32;
  const int gate = lane & 3;
  const int khalf = lane >> 5;
  const int pj = ((tid >> 8) << 1) | ((tid >> 5) & 1);
  const int pm = ((tid >> 6) & 3) * 32 + (tid & 31);
  // xg B-fragments (W1f) -> registers (K=16, constant all steps)
  union BW { unsigned short s[8]; bf16x8 v; } w0f, w1f;
  {
    int g0 = (n0 & 3) * 512 + nt * 32 + (n0 >> 2);
    int g1 = (n1 & 3) * 512 + nt * 32 + (n1 >> 2);
    const float4* s0 = (const float4*)(p.W1f_g + (size_t)g0 * 16 + khalf * 8);
    const float4* s1 = (const float4*)(p.W1f_g + (size_t)g1 * 16 + khalf * 8);
    float4 a = s0[0], b = s0[1], c = s1[0], d = s1[1];
    w0f.s[0] = f2bf(a.x); w0f.s[1] = f2bf(a.y); w0f.s[2] = f2bf(a.z); w0f.s[3] = f2bf(a.w);
    w0f.s[4] = f2bf(b.x); w0f.s[5] = f2bf(b.y); w0f.s[6] = f2bf(b.z); w0f.s[7] = f2bf(b.w);
    w1f.s[0] = f2bf(c.x); w1f.s[1] = f2bf(c.y); w1f.s[2] = f2bf(c.z); w1f.s[3] = f2bf(c.w);
    w1f.s[4] = f2bf(d.x); w1f.s[5] = f2bf(d.y); w1f.s[6] = f2bf(d.z); w1f.s[7] = f2bf(d.w);
  }
  __syncthreads();
  // per-lane hp affine constants (q = lane&31 when <16)
  float sA2q = 0.f, bA2q = 0.f;
  if ((lane & 31) < 16) { sA2q = prm[32 + (lane & 31)]; bA2q = prm[48 + (lane & 31)]; }

  for (int t = 0; t < TSEQ; ++t) {
    if (t > 0) {
      if (wid == 0) {
        const unsigned* fl = p.flags + mt * 32 + (lane & 15);
        while (!__all((int)(ld4(fl) >= (unsigned)t)))
          __builtin_amdgcn_s_sleep(2);
      }
      __syncthreads();
    }

    // ---------- GEMM over h_t: gates (acc0,acc1) + P (accP, wn==0) ----------
    f32x16 acc0, acc1, accP;
    #pragma unroll
    for (int i = 0; i < 16; ++i) { acc0[i] = 0.f; acc1[i] = 0.f; accP[i] = 0.f; }
    {
      const u64* aq = (const u64*)(p.hatom + (size_t)((t + 1) & 1) * 2097152
                                   + mt * 131072) + (wm * 64 + lane) * 2;
      u64 pa[DEPTH], pb[DEPTH];
      #pragma unroll
      for (int c = 0; c < DEPTH; ++c) {
        pa[c] = ld8(aq + c * 512);
        pb[c] = ld8(aq + c * 512 + 1);
      }
      union AB { u64 q[2]; bf16x8 v; };
      #pragma unroll
      for (int c = 0; c < 32; ++c) {
        AB u;
        u.q[0] = pa[c & (DEPTH - 1)];
        u.q[1] = pb[c & (DEPTH - 1)];
        if (c + DEPTH < 32) {
          pa[c & (DEPTH - 1)] = ld8(aq + (c + DEPTH) * 512);
          pb[c & (DEPTH - 1)] = ld8(aq + (c + DEPTH) * 512 + 1);
        }
        int kal = c * 2 + khalf;
        bf16x8 b0 = *(const bf16x8*)(lds + BS_OFF + (((n0 << 6) + (kal ^ (n0 & 7))) << 4));
        bf16x8 b1 = *(const bf16x8*)(lds + BS_OFF + (((n1 << 6) + (kal ^ (n1 & 7))) << 4));
        acc0 = __builtin_amdgcn_mfma_f32_32x32x16_bf16(u.v, b0, acc0, 0, 0, 0);
        acc1 = __builtin_amdgcn_mfma_f32_32x32x16_bf16(u.v, b1, acc1, 0, 0, 0);
        if (wn == 0) {
          bf16x8 bp = {};
          if ((lane & 31) < 16)
            bp = *(const bf16x8*)(lds + HPW_OFF
                  + ((((lane & 31) << 6) + (kal ^ (lane & 7))) << 4));
          accP = __builtin_amdgcn_mfma_f32_32x32x16_bf16(u.v, bp, accP, 0, 0, 0);
        }
      }
    }

    // ---------- lp_t from P (block-local); out[t-1] ----------
    if (t > 0) {
      if (wn == 0 && (lane & 31) < 16) {
        int q = lane & 31;
        #pragma unroll
        for (int r = 0; r < 16; ++r) {
          int row = (r & 3) + 8 * (r >> 2) + 4 * (lane >> 5) + wm * 32;
          h2s[row * 20 + q] = fmaxf(accP[r] * sA2q + bA2q, 0.f);
        }
      }
      __syncthreads();
      if (tid < 256) {
        int m = tid >> 1, c = tid & 1;
        float a2 = prm[128 + c];
        const float4* hrow = (const float4*)(lds + UNI_OFF + m * 80);
        #pragma unroll
        for (int g4 = 0; g4 < 4; ++g4) {
          float4 v = hrow[g4];
          a2 += v.x * prm[96 + (g4 * 4 + 0) * 2 + c];
          a2 += v.y * prm[96 + (g4 * 4 + 1) * 2 + c];
          a2 += v.z * prm[96 + (g4 * 4 + 2) * 2 + c];
          a2 += v.w * prm[96 + (g4 * 4 + 3) * 2 + c];
        }
        float lpv = 1.f / (1.f + __expf(-(a2 + lps[tid])));
        lps[tid] = lpv;
        if (nt == 0) p.out[((size_t)(t - 1) * BATCH + m0 + m) * 2 + c] = lpv;
      }
      __syncthreads();
    }

    // ---------- h1 = relu(affine(lp @ se_w1)) ----------
    #pragma unroll
    for (int u = 0; u < 4; ++u) {
      int id = u * NTHR + tid;
      int m = id >> 4, q = id & 15;
      float z = lps[m * 2] * prm[64 + q] + lps[m * 2 + 1] * prm[80 + q];
      h1s[m * 16 + q] = (unsigned short)f2bf(fmaxf(z * prm[q] + prm[16 + q], 0.f));
    }
    __syncthreads();

    // ---------- xg contribution (last MFMA) ----------
    {
      bf16x8 a1 = *(const bf16x8*)(lds + H1_OFF + (wm * 32 + (lane & 31)) * 32 + khalf * 16);
      acc0 = __builtin_amdgcn_mfma_f32_32x32x16_bf16(a1, w0f.v, acc0, 0, 0, 0);
      acc1 = __builtin_amdgcn_mfma_f32_32x32x16_bf16(a1, w1f.v, acc1, 0, 0, 0);
    }

    // ---------- epilogue: LSTM cell update ----------
    #pragma unroll
    for (int t2 = 0; t2 < 2; ++t2) {
      float bias = biasr[t2];
      int jj = (wn * 64 + t2 * 32 + (lane & 31)) >> 2;
      float act[16];
      const f32x16& A = (t2 == 0) ? acc0 : acc1;
      #pragma unroll
      for (int r = 0; r < 16; ++r) {
        float v = A[r] + bias;
        float vv = (gate == 2) ? 2.f * v : v;
        float sg = 1.f / (1.f + __expf(-vv));
        act[r] = (gate == 2) ? 2.f * sg - 1.f : sg;
      }
      #pragma unroll
      for (int r = 0; r < 16; ++r) {
        float iv = QB(act[r], 0x00);
        float fv = QB(act[r], 0x55);
        float gv = QB(act[r], 0xAA);
        float ov = QB(act[r], 0xFF);
        float cn = fv * c_st[t2][r] + iv * gv;
        c_st[t2][r] = cn;
        float th = 2.f / (1.f + __expf(-2.f * cn)) - 1.f;
        float hn = ov * th;
        if ((lane & 3) == 0) {
          int row = (r & 3) + 8 * (r >> 2) + 4 * (lane >> 5) + wm * 32;
          hPsh[row * 36 + jj] = (unsigned short)f2bf(hn);
        }
      }
    }
    __syncthreads();

    // ---------- coalesced h-atom stores + flag ----------
    {
      const u64* hp8 = (const u64*)(lds + UNI_OFF + pm * 72 + pj * 16);
      u64* hdst = (u64*)(p.hatom + (size_t)(t & 1) * 2097152 + mt * 131072);
      st8(hdst + (512 * nt + tid) * 2,     hp8[0]);
      st8(hdst + (512 * nt + tid) * 2 + 1, hp8[1]);
    }
    __syncthreads();   // implicit vmcnt(0) drains the sc1 stores
    if (tid == 0) st4(p.flags + mt * 32 + nt, (unsigned)(t + 1));
  }

  // ---------- tail (t=32): P(h_32) only -> lp_32 -> out[31] ----------
  {
    if (wid == 0) {
      const unsigned* fl = p.flags + mt * 32 + (lane & 15);
      while (!__all((int)(ld4(fl) >= (unsigned)TSEQ)))
        __builtin_amdgcn_s_sleep(2);
    }
    __syncthreads();
    f32x16 accP;
    #pragma unroll
    for (int i = 0; i < 16; ++i) accP[i] = 0.f;
    if (wn == 0) {
      const u64* aq = (const u64*)(p.hatom + 2097152 + mt * 131072)
                      + (wm * 64 + lane) * 2;
      u64 pa[8], pb[8];
      #pragma unroll
      for (int c = 0; c < 8; ++c) {
        pa[c] = ld8(aq + c * 512);
        pb[c] = ld8(aq + c * 512 + 1);
      }
      union AB { u64 q[2]; bf16x8 v; };
      #pragma unroll
      for (int c = 0; c < 32; ++c) {
        AB u;
        u.q[0] = pa[c & 7];
        u.q[1] = pb[c & 7];
        if (c + 8 < 32) {
          pa[c & 7] = ld8(aq + (c + 8) * 512);
          pb[c & 7] = ld8(aq + (c + 8) * 512 + 1);
        }
        int kal = c * 2 + khalf;
        bf16x8 bp = {};
        if ((lane & 31) < 16)
          bp = *(const bf16x8*)(lds + HPW_OFF
                + ((((lane & 31) << 6) + (kal ^ (lane & 7))) << 4));
        accP = __builtin_amdgcn_mfma_f32_32x32x16_bf16(u.v, bp, accP, 0, 0, 0);
      }
      if ((lane & 31) < 16) {
        int q = lane & 31;
        #pragma unroll
        for (int r = 0; r < 16; ++r) {
          int row = (r & 3) + 8 * (r >> 2) + 4 * (lane >> 5) + wm * 32;
          h2s[row * 20 + q] = fmaxf(accP[r] * sA2q + bA2q, 0.f);
        }
      }
    }
    __syncthreads();
    if (tid < 256 && nt == 0) {
      int m = tid >> 1, c = tid & 1;
      float a2 = prm[128 + c];
      const float4* hrow = (const float4*)(lds + UNI_OFF + m * 80);
      #pragma unroll
      for (int g4 = 0; g4 < 4; ++g4) {
        float4 v = hrow[g4];
        a2 += v.x * prm[96 + (g4 * 4 + 0) * 2 + c];
        a2 += v.y * prm[96 + (g4 * 4 + 1) * 2 + c];
        a2 += v.z * prm[96 + (g4 * 4 + 2) * 2 + c];
        a2 += v.w * prm[96 + (g4 * 4 + 3) * 2 + c];
      }
      float lpv = 1.f / (1.f + __expf(-(a2 + lps[tid])));
      p.out[((size_t)(TSEQ - 1) * BATCH + m0 + m) * 2 + c] = lpv;
    }
  }
}

// ---------------------------------------------------------------------------
extern "C" void kernel_launch(void* const* d_in, const int* in_sizes, int n_in,
                              void* d_out, int out_size, void* d_ws, size_t ws_size,
                              hipStream_t stream) {
  char* ws = (char*)d_ws;
  const float* last_pos = (const float*)d_in[0];
  const float* hh    = (const float*)d_in[1];
  const float* ch    = (const float*)d_in[2];
  const float* se_w1 = (const float*)d_in[3];
  const float* se_b1 = (const float*)d_in[4];
  const float* se_g  = (const float*)d_in[5];
  const float* se_bt = (const float*)d_in[6];
  const float* se_m  = (const float*)d_in[7];
  const float* se_v  = (const float*)d_in[8];
  const float* se_w2 = (const float*)d_in[9];
  const float* se_b2 = (const float*)d_in[10];
  const float* w_ih  = (const float*)d_in[11];
  const float* w_hh  = (const float*)d_in[12];
  const float* b_ih  = (const float*)d_in[13];
  const float* b_hh  = (const float*)d_in[14];
  const float* hp_w1 = (const float*)d_in[15];
  const float* hp_b1 = (const float*)d_in[16];
  const float* hp_g  = (const float*)d_in[17];
  const float* hp_bt = (const float*)d_in[18];
  const float* hp_m  = (const float*)d_in[19];
  const float* hp_v  = (const float*)d_in[20];
  const float* hp_w2 = (const float*)d_in[21];
  const float* hp_b2 = (const float*)d_in[22];

  float* W1f_g  = (float*)(ws + WS_W1F);
  float* bias_f = (float*)(ws + WS_BIASF);
  unsigned* flags = (unsigned*)(ws + WS_FLAGS);
  char* hatom   = ws + WS_HATOM;

  (void)hipMemsetAsync(ws + WS_FLAGS, 0, 2048, stream);
  decoder_setup<<<dim3(320), dim3(256), 0, stream>>>(
      w_ih, se_w2, se_b2, b_ih, b_hh, hh, W1f_g, bias_f, hatom);

  (void)hipFuncSetAttribute((const void*)decoder_persist,
                            hipFuncAttributeMaxDynamicSharedMemorySize, LDS_TOTAL);

  KParams kp;
  kp.last_pos = last_pos; kp.ch0 = ch; kp.w_hh = w_hh;
  kp.se_w1 = se_w1; kp.se_b1 = se_b1; kp.se_g = se_g; kp.se_bt = se_bt;
  kp.se_m = se_m; kp.se_v = se_v;
  kp.hp_w1 = hp_w1; kp.hp_b1 = hp_b1; kp.hp_g = hp_g; kp.hp_bt = hp_bt;
  kp.hp_m = hp_m; kp.hp_v = hp_v; kp.hp_w2 = hp_w2; kp.hp_b2 = hp_b2;
  kp.W1f_g = W1f_g; kp.bias_f = bias_f;
  kp.hatom = hatom; kp.flags = flags; kp.out = (float*)d_out;

  void* args[] = { &kp };
  (void)hipLaunchCooperativeKernel((void*)decoder_persist, dim3(NBLK), dim3(NTHR),
                                   args, LDS_TOTAL, stream);
}

// Round 8
// 615.934 us; speedup vs baseline: 2.5510x; 1.0599x over previous
//
#include <hip/hip_runtime.h>

// ============================================================================
// Decoder_70437463654609: 32-step LSTM recurrence, B=2048 H=512 HID=16.
// R8 = R7 + cached A-path: A-atom loads are plain (L2-cached) loads; staleness
// handled by ONE `buffer_inv sc1` per block per step after the flag wait.
// h-atom stores remain sc0sc1 write-through (L2 never dirty-stale, MALL always
// current). out-stores also sc0sc1 so no dirty L2 lines exist near the inv.
// ============================================================================

#define TSEQ  32
#define BATCH 2048
#define HDIM  512
#define GDIM  2048   // 4*H
#define NBLK  256
#define NTHR  512
#define DEPTH 8      // A-prefetch pipeline depth (K16 chunks) — L2-hit latency

typedef __bf16 bf16x8 __attribute__((ext_vector_type(8)));
typedef float  f32x16 __attribute__((ext_vector_type(16)));
typedef unsigned long long u64;

// ---- LDS layout (byte offsets), total 163,360 <= 163,840 ----
#define BS_OFF     0          // Bs: w_hh slice [128 n][64 k8 atoms x 16B], swz (131072)
#define HPW_OFF    131072     // hp_w1 atoms [16 n][64 k8 x 16B], swz (16384)
#define UNI_OFF    147456     // union: h2s [128][20] f32 (10240) | hP bf16 [128][36] (9216)
#define H1_OFF     157696     // h1s [128 m][16 bf16] stride 32 B (4096)
#define LPS_OFF    161792     // lps [128][2] f32 (1024)
#define PRM_OFF    162816     // folded params (130 f32) (544)
#define LDS_TOTAL  163360

// ---- workspace layout (bytes) ----
#define WS_W1F    0                        // [2048][16] f32 : se_w2 @ w_ih^T
#define WS_BIASF  131072                   // [2048] f32
#define WS_FLAGS  139264                   // 16 groups x 128 B
#define WS_HATOM  141312                   // 2 x (16 mt x 128 KB)  h atoms

__device__ __forceinline__ unsigned f2bf(float f) {   // RNE f32->bf16 (low 16)
  unsigned u = __float_as_uint(f);
  u += 0x7fffu + ((u >> 16) & 1u);
  return u >> 16;
}
__device__ __forceinline__ float bf2f(unsigned short b) {
  return __uint_as_float(((unsigned)b) << 16);
}
// relaxed agent-scope ops -> global_load/store ... sc0 sc1 (device-coherent)
__device__ __forceinline__ u64 ld8(const void* p) {
  return __hip_atomic_load((const u64*)p, __ATOMIC_RELAXED, __HIP_MEMORY_SCOPE_AGENT);
}
__device__ __forceinline__ void st8(void* p, u64 v) {
  __hip_atomic_store((u64*)p, v, __ATOMIC_RELAXED, __HIP_MEMORY_SCOPE_AGENT);
}
__device__ __forceinline__ unsigned ld4(const unsigned* p) {
  return __hip_atomic_load(p, __ATOMIC_RELAXED, __HIP_MEMORY_SCOPE_AGENT);
}
__device__ __forceinline__ void st4(unsigned* p, unsigned v) {
  __hip_atomic_store(p, v, __ATOMIC_RELAXED, __HIP_MEMORY_SCOPE_AGENT);
}
// invalidate this XCD's L2 (agent-acquire maintenance op; no operands/regs)
__device__ __forceinline__ void l2_inv() {
  asm volatile("buffer_inv sc1" ::: "memory");
}
// quad-perm broadcast
#define QB(x, imm) __uint_as_float((unsigned)__builtin_amdgcn_mov_dpp((int)__float_as_uint(x), imm, 0xF, 0xF, true))

struct KParams {
  const float *last_pos, *ch0, *w_hh;
  const float *se_w1, *se_b1, *se_g, *se_bt, *se_m, *se_v;
  const float *hp_w1, *hp_b1, *hp_g, *hp_bt, *hp_m, *hp_v, *hp_w2, *hp_b2;
  const float *W1f_g, *bias_f;
  char* hatom;            // 2 parities x 2 MB
  unsigned* flags;        // 16 x 32 u32
  float* out;
};

// ---------------------------------------------------------------------------
// Setup <<<320, 256>>>: blocks 0..255: W1f/bias (8 gate-rows each, LDS-staged,
// fully parallel dots). blocks 256..319: h0 -> atom layout (parity 1).
// ---------------------------------------------------------------------------
__global__ __launch_bounds__(256) void decoder_setup(
    const float* __restrict__ w_ih, const float* __restrict__ se_w2,
    const float* __restrict__ se_b2, const float* __restrict__ b_ih,
    const float* __restrict__ b_hh, const float* __restrict__ hh,
    float* __restrict__ W1f_g, float* __restrict__ bias_f,
    char* __restrict__ hatom) {
  int bid = blockIdx.x, tid = threadIdx.x;
  if (bid < 256) {
    __shared__ float wrow[8 * 512];
    __shared__ float ps[256];
    __shared__ float psB[128];
    int r0 = bid * 8;
    #pragma unroll
    for (int i = 0; i < 4; ++i) {
      int idx = i * 256 + tid;
      ((float4*)wrow)[idx] = ((const float4*)(w_ih + (size_t)r0 * 512))[idx];
    }
    __syncthreads();
    {
      int r = tid >> 5, q = (tid >> 1) & 15, half = tid & 1;
      const float* sw = se_w2 + (size_t)q * 512 + half * 256;
      const float* wr = wrow + r * 512 + half * 256;
      float s = 0.f;
      #pragma unroll 8
      for (int e = 0; e < 256; ++e) s += sw[e] * wr[e];
      ps[tid] = s;
    }
    if (tid < 128) {
      int r = tid >> 4, seg = tid & 15;
      const float* wr = wrow + r * 512 + seg * 32;
      const float* sb = se_b2 + seg * 32;
      float s = 0.f;
      #pragma unroll
      for (int e = 0; e < 32; ++e) s += sb[e] * wr[e];
      psB[tid] = s;
    }
    __syncthreads();
    if (tid < 128) {
      int r = tid >> 4, q = tid & 15;
      W1f_g[(r0 + r) * 16 + q] = ps[r * 32 + q * 2] + ps[r * 32 + q * 2 + 1];
    } else if (tid < 136) {
      int r = tid - 128;
      float s = 0.f;
      #pragma unroll
      for (int i = 0; i < 16; ++i) s += psB[r * 16 + i];
      bias_f[r0 + r] = s + b_ih[r0 + r] + b_hh[r0 + r];
    }
  } else {
    int bb = bid - 256;
    for (int u = 0; u < 8; ++u) {
      int aidx = bb * 2048 + u * 256 + tid;     // 131072 atoms total
      int mtl = aidx >> 13, a = aidx & 8191;
      int lane = a & 63, slot = a >> 6;
      int m = (slot & 3) * 32 + (lane & 31);
      int k8 = (slot >> 2) * 2 + (lane >> 5);
      const float* s8 = hh + (size_t)mtl * 65536 + (size_t)m * 512 + k8 * 8;
      uint4 v;
      v.x = f2bf(s8[0]) | (f2bf(s8[1]) << 16);
      v.y = f2bf(s8[2]) | (f2bf(s8[3]) << 16);
      v.z = f2bf(s8[4]) | (f2bf(s8[5]) << 16);
      v.w = f2bf(s8[6]) | (f2bf(s8[7]) << 16);
      *(uint4*)(hatom + 2097152 + (size_t)mtl * 131072 + (size_t)a * 16) = v;
    }
  }
}

// ---------------------------------------------------------------------------
// Persistent kernel. 256 blocks x 512 threads, 1 block/CU.
// Block (mt, nt): rows [mt*128,+128), local n = 4*jj + gate.
// ---------------------------------------------------------------------------
__global__ __launch_bounds__(NTHR, 2) void decoder_persist(KParams p) {
  extern __shared__ char lds[];
  const int tid  = threadIdx.x;
  const int lane = tid & 63;
  const int wid  = tid >> 6;
  const int wm   = wid >> 1;
  const int wn   = wid & 1;
  const int mt   = blockIdx.x >> 4;
  const int nt   = blockIdx.x & 15;
  const int m0   = mt * 128;

  float* prm = (float*)(lds + PRM_OFF);
  float* lps = (float*)(lds + LPS_OFF);
  float* h2s = (float*)(lds + UNI_OFF);                   // stride 20 f32
  unsigned short* hPsh = (unsigned short*)(lds + UNI_OFF); // stride 36 u16
  unsigned short* h1s  = (unsigned short*)(lds + H1_OFF);  // stride 16 u16

  // ---------------- one-time init ----------------
  if (tid < 16) {
    int q = tid;
    float sA = p.se_g[q] * rsqrtf(p.se_v[q] + 1e-5f);
    prm[q]      = sA;
    prm[16 + q] = (p.se_b1[q] - p.se_m[q]) * sA + p.se_bt[q];
    float hA = p.hp_g[q] * rsqrtf(p.hp_v[q] + 1e-5f);
    prm[32 + q] = hA;
    prm[48 + q] = (p.hp_b1[q] - p.hp_m[q]) * hA + p.hp_bt[q];
  }
  if (tid < 32) { prm[64 + tid] = p.se_w1[tid]; prm[96 + tid] = p.hp_w2[tid]; }
  if (tid < 2)  { prm[128 + tid] = p.hp_b2[tid]; }
  if (tid < 256) lps[tid] = p.last_pos[(size_t)m0 * 2 + tid];
  float biasr[2];
  #pragma unroll
  for (int t2 = 0; t2 < 2; ++t2) {
    int n = wn * 64 + t2 * 32 + (lane & 31);
    int grow = (n & 3) * 512 + nt * 32 + (n >> 2);
    biasr[t2] = p.bias_f[grow];
  }
  // Bs: w_hh slice -> bf16 atoms (n, k8) at n*64 + (k8 ^ (n&7))
  for (int a = tid; a < 8192; a += NTHR) {
    int n = a >> 6, ka = a & 63;
    int grow = (n & 3) * 512 + nt * 32 + (n >> 2);
    const float* src = p.w_hh + (size_t)grow * 512 + ka * 8;
    uint4 v;
    v.x = f2bf(src[0]) | (f2bf(src[1]) << 16);
    v.y = f2bf(src[2]) | (f2bf(src[3]) << 16);
    v.z = f2bf(src[4]) | (f2bf(src[5]) << 16);
    v.w = f2bf(src[6]) | (f2bf(src[7]) << 16);
    *(uint4*)(lds + BS_OFF + ((size_t)(n * 64 + (ka ^ (n & 7)))) * 16) = v;
  }
  // hp_w1 atoms: atom (n<16, k8) = hp_w1[k8*8+j][n], j=0..7 (stride 16 floats)
  for (int a = tid; a < 1024; a += NTHR) {
    int n = a >> 6, k8 = a & 63;
    const float* src = p.hp_w1 + (size_t)(k8 * 8) * 16 + n;
    uint4 v;
    v.x = f2bf(src[0])   | (f2bf(src[16]) << 16);
    v.y = f2bf(src[32])  | (f2bf(src[48]) << 16);
    v.z = f2bf(src[64])  | (f2bf(src[80]) << 16);
    v.w = f2bf(src[96])  | (f2bf(src[112]) << 16);
    *(uint4*)(lds + HPW_OFF + ((size_t)(n * 64 + (k8 ^ (n & 7)))) * 16) = v;
  }
  // c state (lanes with lane%4==0), 16 rows x 2 tiles
  float c_st[2][16];
  #pragma unroll
  for (int t2 = 0; t2 < 2; ++t2)
    #pragma unroll
    for (int r = 0; r < 16; ++r) c_st[t2][r] = 0.f;
  if ((lane & 3) == 0) {
    #pragma unroll
    for (int t2 = 0; t2 < 2; ++t2) {
      int n_loc = wn * 64 + t2 * 32 + (lane & 31);
      int jj = n_loc >> 2;
      #pragma unroll
      for (int r = 0; r < 16; ++r) {
        int row = (r & 3) + 8 * (r >> 2) + 4 * (lane >> 5) + wm * 32;
        c_st[t2][r] = p.ch0[(size_t)(m0 + row) * 512 + nt * 32 + jj];
      }
    }
  }
  const int n0 = wn * 64 + (lane & 31);
  const int n1 = n0 + 32;
  const int gate = lane & 3;
  const int khalf = lane >> 5;
  const int pj = ((tid >> 8) << 1) | ((tid >> 5) & 1);
  const int pm = ((tid >> 6) & 3) * 32 + (tid & 31);
  // xg B-fragments (W1f) -> registers (K=16, constant all steps)
  union BW { unsigned short s[8]; bf16x8 v; } w0f, w1f;
  {
    int g0 = (n0 & 3) * 512 + nt * 32 + (n0 >> 2);
    int g1 = (n1 & 3) * 512 + nt * 32 + (n1 >> 2);
    const float4* s0 = (const float4*)(p.W1f_g + (size_t)g0 * 16 + khalf * 8);
    const float4* s1 = (const float4*)(p.W1f_g + (size_t)g1 * 16 + khalf * 8);
    float4 a = s0[0], b = s0[1], c = s1[0], d = s1[1];
    w0f.s[0] = f2bf(a.x); w0f.s[1] = f2bf(a.y); w0f.s[2] = f2bf(a.z); w0f.s[3] = f2bf(a.w);
    w0f.s[4] = f2bf(b.x); w0f.s[5] = f2bf(b.y); w0f.s[6] = f2bf(b.z); w0f.s[7] = f2bf(b.w);
    w1f.s[0] = f2bf(c.x); w1f.s[1] = f2bf(c.y); w1f.s[2] = f2bf(c.z); w1f.s[3] = f2bf(c.w);
    w1f.s[4] = f2bf(d.x); w1f.s[5] = f2bf(d.y); w1f.s[6] = f2bf(d.z); w1f.s[7] = f2bf(d.w);
  }
  __syncthreads();
  // per-lane hp affine constants (q = lane&31 when <16)
  float sA2q = 0.f, bA2q = 0.f;
  if ((lane & 31) < 16) { sA2q = prm[32 + (lane & 31)]; bA2q = prm[48 + (lane & 31)]; }

  for (int t = 0; t < TSEQ; ++t) {
    if (t > 0) {
      if (wid == 0) {
        const unsigned* fl = p.flags + mt * 32 + (lane & 15);
        while (!__all((int)(ld4(fl) >= (unsigned)t)))
          __builtin_amdgcn_s_sleep(2);
        l2_inv();          // drop stale A lines in this XCD's L2; MALL is current
      }
      __syncthreads();
    }

    // ---------- GEMM over h_t: gates (acc0,acc1) + P (accP, wn==0) ----------
    f32x16 acc0, acc1, accP;
    #pragma unroll
    for (int i = 0; i < 16; ++i) { acc0[i] = 0.f; acc1[i] = 0.f; accP[i] = 0.f; }
    {
      const char* abase = p.hatom + (size_t)((t + 1) & 1) * 2097152 + mt * 131072
                          + (wm * 64 + lane) * 16;
      uint4 pre[DEPTH];
      #pragma unroll
      for (int c = 0; c < DEPTH; ++c) pre[c] = *(const uint4*)(abase + c * 4096);
      union AB { uint4 u; bf16x8 v; };
      #pragma unroll
      for (int c = 0; c < 32; ++c) {
        AB u;
        u.u = pre[c & (DEPTH - 1)];
        if (c + DEPTH < 32)
          pre[c & (DEPTH - 1)] = *(const uint4*)(abase + (c + DEPTH) * 4096);
        int kal = c * 2 + khalf;
        bf16x8 b0 = *(const bf16x8*)(lds + BS_OFF + (((n0 << 6) + (kal ^ (n0 & 7))) << 4));
        bf16x8 b1 = *(const bf16x8*)(lds + BS_OFF + (((n1 << 6) + (kal ^ (n1 & 7))) << 4));
        acc0 = __builtin_amdgcn_mfma_f32_32x32x16_bf16(u.v, b0, acc0, 0, 0, 0);
        acc1 = __builtin_amdgcn_mfma_f32_32x32x16_bf16(u.v, b1, acc1, 0, 0, 0);
        if (wn == 0) {
          bf16x8 bp = {};
          if ((lane & 31) < 16)
            bp = *(const bf16x8*)(lds + HPW_OFF
                  + ((((lane & 31) << 6) + (kal ^ (lane & 7))) << 4));
          accP = __builtin_amdgcn_mfma_f32_32x32x16_bf16(u.v, bp, accP, 0, 0, 0);
        }
      }
    }

    // ---------- lp_t from P (block-local); out[t-1] ----------
    if (t > 0) {
      if (wn == 0 && (lane & 31) < 16) {
        int q = lane & 31;
        #pragma unroll
        for (int r = 0; r < 16; ++r) {
          int row = (r & 3) + 8 * (r >> 2) + 4 * (lane >> 5) + wm * 32;
          h2s[row * 20 + q] = fmaxf(accP[r] * sA2q + bA2q, 0.f);
        }
      }
      __syncthreads();
      if (tid < 256) {
        int m = tid >> 1, c = tid & 1;
        float a2 = prm[128 + c];
        const float4* hrow = (const float4*)(lds + UNI_OFF + m * 80);
        #pragma unroll
        for (int g4 = 0; g4 < 4; ++g4) {
          float4 v = hrow[g4];
          a2 += v.x * prm[96 + (g4 * 4 + 0) * 2 + c];
          a2 += v.y * prm[96 + (g4 * 4 + 1) * 2 + c];
          a2 += v.z * prm[96 + (g4 * 4 + 2) * 2 + c];
          a2 += v.w * prm[96 + (g4 * 4 + 3) * 2 + c];
        }
        float lpv = 1.f / (1.f + __expf(-(a2 + lps[tid])));
        lps[tid] = lpv;
        if (nt == 0)   // sc0sc1 store: never leaves a dirty L2 line near inv
          st4((unsigned*)&p.out[((size_t)(t - 1) * BATCH + m0 + m) * 2 + c],
              __float_as_uint(lpv));
      }
      __syncthreads();
    }

    // ---------- h1 = relu(affine(lp @ se_w1)) ----------
    #pragma unroll
    for (int u = 0; u < 4; ++u) {
      int id = u * NTHR + tid;
      int m = id >> 4, q = id & 15;
      float z = lps[m * 2] * prm[64 + q] + lps[m * 2 + 1] * prm[80 + q];
      h1s[m * 16 + q] = (unsigned short)f2bf(fmaxf(z * prm[q] + prm[16 + q], 0.f));
    }
    __syncthreads();

    // ---------- xg contribution (last MFMA) ----------
    {
      bf16x8 a1 = *(const bf16x8*)(lds + H1_OFF + (wm * 32 + (lane & 31)) * 32 + khalf * 16);
      acc0 = __builtin_amdgcn_mfma_f32_32x32x16_bf16(a1, w0f.v, acc0, 0, 0, 0);
      acc1 = __builtin_amdgcn_mfma_f32_32x32x16_bf16(a1, w1f.v, acc1, 0, 0, 0);
    }

    // ---------- epilogue: LSTM cell update ----------
    #pragma unroll
    for (int t2 = 0; t2 < 2; ++t2) {
      float bias = biasr[t2];
      int jj = (wn * 64 + t2 * 32 + (lane & 31)) >> 2;
      float act[16];
      const f32x16& A = (t2 == 0) ? acc0 : acc1;
      #pragma unroll
      for (int r = 0; r < 16; ++r) {
        float v = A[r] + bias;
        float vv = (gate == 2) ? 2.f * v : v;
        float sg = 1.f / (1.f + __expf(-vv));
        act[r] = (gate == 2) ? 2.f * sg - 1.f : sg;
      }
      #pragma unroll
      for (int r = 0; r < 16; ++r) {
        float iv = QB(act[r], 0x00);
        float fv = QB(act[r], 0x55);
        float gv = QB(act[r], 0xAA);
        float ov = QB(act[r], 0xFF);
        float cn = fv * c_st[t2][r] + iv * gv;
        c_st[t2][r] = cn;
        float th = 2.f / (1.f + __expf(-2.f * cn)) - 1.f;
        float hn = ov * th;
        if ((lane & 3) == 0) {
          int row = (r & 3) + 8 * (r >> 2) + 4 * (lane >> 5) + wm * 32;
          hPsh[row * 36 + jj] = (unsigned short)f2bf(hn);
        }
      }
    }
    __syncthreads();

    // ---------- coalesced h-atom stores (sc0sc1 write-through) + flag ----------
    {
      const u64* hp8 = (const u64*)(lds + UNI_OFF + pm * 72 + pj * 16);
      u64* hdst = (u64*)(p.hatom + (size_t)(t & 1) * 2097152 + mt * 131072);
      st8(hdst + (512 * nt + tid) * 2,     hp8[0]);
      st8(hdst + (512 * nt + tid) * 2 + 1, hp8[1]);
    }
    __syncthreads();   // implicit vmcnt(0) drains the sc1 stores
    if (tid == 0) st4(p.flags + mt * 32 + nt, (unsigned)(t + 1));
  }

  // ---------- tail (t=32): P(h_32) only -> lp_32 -> out[31] ----------
  {
    if (wid == 0) {
      const unsigned* fl = p.flags + mt * 32 + (lane & 15);
      while (!__all((int)(ld4(fl) >= (unsigned)TSEQ)))
        __builtin_amdgcn_s_sleep(2);
      l2_inv();
    }
    __syncthreads();
    f32x16 accP;
    #pragma unroll
    for (int i = 0; i < 16; ++i) accP[i] = 0.f;
    if (wn == 0) {
      const char* abase = p.hatom + 2097152 + mt * 131072 + (wm * 64 + lane) * 16;
      uint4 pre[DEPTH];
      #pragma unroll
      for (int c = 0; c < DEPTH; ++c) pre[c] = *(const uint4*)(abase + c * 4096);
      union AB { uint4 u; bf16x8 v; };
      #pragma unroll
      for (int c = 0; c < 32; ++c) {
        AB u;
        u.u = pre[c & (DEPTH - 1)];
        if (c + DEPTH < 32)
          pre[c & (DEPTH - 1)] = *(const uint4*)(abase + (c + DEPTH) * 4096);
        int kal = c * 2 + khalf;
        bf16x8 bp = {};
        if ((lane & 31) < 16)
          bp = *(const bf16x8*)(lds + HPW_OFF
                + ((((lane & 31) << 6) + (kal ^ (lane & 7))) << 4));
        accP = __builtin_amdgcn_mfma_f32_32x32x16_bf16(u.v, bp, accP, 0, 0, 0);
      }
      if ((lane & 31) < 16) {
        int q = lane & 31;
        #pragma unroll
        for (int r = 0; r < 16; ++r) {
          int row = (r & 3) + 8 * (r >> 2) + 4 * (lane >> 5) + wm * 32;
          h2s[row * 20 + q] = fmaxf(accP[r] * sA2q + bA2q, 0.f);
        }
      }
    }
    __syncthreads();
    if (tid < 256 && nt == 0) {
      int m = tid >> 1, c = tid & 1;
      float a2 = prm[128 + c];
      const float4* hrow = (const float4*)(lds + UNI_OFF + m * 80);
      #pragma unroll
      for (int g4 = 0; g4 < 4; ++g4) {
        float4 v = hrow[g4];
        a2 += v.x * prm[96 + (g4 * 4 + 0) * 2 + c];
        a2 += v.y * prm[96 + (g4 * 4 + 1) * 2 + c];
        a2 += v.z * prm[96 + (g4 * 4 + 2) * 2 + c];
        a2 += v.w * prm[96 + (g4 * 4 + 3) * 2 + c];
      }
      float lpv = 1.f / (1.f + __expf(-(a2 + lps[tid])));
      st4((unsigned*)&p.out[((size_t)(TSEQ - 1) * BATCH + m0 + m) * 2 + c],
          __float_as_uint(lpv));
    }
  }
}

// ---------------------------------------------------------------------------
extern "C" void kernel_launch(void* const* d_in, const int* in_sizes, int n_in,
                              void* d_out, int out_size, void* d_ws, size_t ws_size,
                              hipStream_t stream) {
  char* ws = (char*)d_ws;
  const float* last_pos = (const float*)d_in[0];
  const float* hh    = (const float*)d_in[1];
  const float* ch    = (const float*)d_in[2];
  const float* se_w1 = (const float*)d_in[3];
  const float* se_b1 = (const float*)d_in[4];
  const float* se_g  = (const float*)d_in[5];
  const float* se_bt = (const float*)d_in[6];
  const float* se_m  = (const float*)d_in[7];
  const float* se_v  = (const float*)d_in[8];
  const float* se_w2 = (const float*)d_in[9];
  const float* se_b2 = (const float*)d_in[10];
  const float* w_ih  = (const float*)d_in[11];
  const float* w_hh  = (const float*)d_in[12];
  const float* b_ih  = (const float*)d_in[13];
  const float* b_hh  = (const float*)d_in[14];
  const float* hp_w1 = (const float*)d_in[15];
  const float* hp_b1 = (const float*)d_in[16];
  const float* hp_g  = (const float*)d_in[17];
  const float* hp_bt = (const float*)d_in[18];
  const float* hp_m  = (const float*)d_in[19];
  const float* hp_v  = (const float*)d_in[20];
  const float* hp_w2 = (const float*)d_in[21];
  const float* hp_b2 = (const float*)d_in[22];

  float* W1f_g  = (float*)(ws + WS_W1F);
  float* bias_f = (float*)(ws + WS_BIASF);
  unsigned* flags = (unsigned*)(ws + WS_FLAGS);
  char* hatom   = ws + WS_HATOM;

  (void)hipMemsetAsync(ws + WS_FLAGS, 0, 2048, stream);
  decoder_setup<<<dim3(320), dim3(256), 0, stream>>>(
      w_ih, se_w2, se_b2, b_ih, b_hh, hh, W1f_g, bias_f, hatom);

  (void)hipFuncSetAttribute((const void*)decoder_persist,
                            hipFuncAttributeMaxDynamicSharedMemorySize, LDS_TOTAL);

  KParams kp;
  kp.last_pos = last_pos; kp.ch0 = ch; kp.w_hh = w_hh;
  kp.se_w1 = se_w1; kp.se_b1 = se_b1; kp.se_g = se_g; kp.se_bt = se_bt;
  kp.se_m = se_m; kp.se_v = se_v;
  kp.hp_w1 = hp_w1; kp.hp_b1 = hp_b1; kp.hp_g = hp_g; kp.hp_bt = hp_bt;
  kp.hp_m = hp_m; kp.hp_v = hp_v; kp.hp_w2 = hp_w2; kp.hp_b2 = hp_b2;
  kp.W1f_g = W1f_g; kp.bias_f = bias_f;
  kp.hatom = hatom; kp.flags = flags; kp.out = (float*)d_out;

  void* args[] = { &kp };
  (void)hipLaunchCooperativeKernel((void*)decoder_persist, dim3(NBLK), dim3(NTHR),
                                   args, LDS_TOTAL, stream);
}

// Round 9
// 587.059 us; speedup vs baseline: 2.6765x; 1.0492x over previous
//
#include <hip/hip_runtime.h>

// ============================================================================
// Decoder_70437463654609: 32-step LSTM recurrence, B=2048 H=512 HID=16.
// R9 = R8 + (1) plain launch (probe ~146us cooperative-launch gap),
//      (2) fine-grained per-producer flag gating woven into the K-loop
//          (ballot readiness mask, rotated chunk order starting at own nt),
//      (3) l2_inv moved to end-of-step (after flag post) — cached A-loads kept.
// ============================================================================

#define TSEQ  32
#define BATCH 2048
#define HDIM  512
#define GDIM  2048   // 4*H
#define NBLK  256
#define NTHR  512
#define DEPTH 8      // A-prefetch pipeline depth (K16 chunks) = 4 producer groups

typedef __bf16 bf16x8 __attribute__((ext_vector_type(8)));
typedef float  f32x16 __attribute__((ext_vector_type(16)));
typedef unsigned long long u64;

// ---- LDS layout (byte offsets), total 163,360 <= 163,840 ----
#define BS_OFF     0          // Bs: w_hh slice [128 n][64 k8 atoms x 16B], swz (131072)
#define HPW_OFF    131072     // hp_w1 atoms [16 n][64 k8 x 16B], swz (16384)
#define UNI_OFF    147456     // union: h2s [128][20] f32 (10240) | hP bf16 [128][36] (9216)
#define H1_OFF     157696     // h1s [128 m][16 bf16] stride 32 B (4096)
#define LPS_OFF    161792     // lps [128][2] f32 (1024)
#define PRM_OFF    162816     // folded params (130 f32) (544)
#define LDS_TOTAL  163360

// ---- workspace layout (bytes) ----
#define WS_W1F    0                        // [2048][16] f32 : se_w2 @ w_ih^T
#define WS_BIASF  131072                   // [2048] f32
#define WS_FLAGS  139264                   // 16 groups x 128 B
#define WS_HATOM  141312                   // 2 x (16 mt x 128 KB)  h atoms

__device__ __forceinline__ unsigned f2bf(float f) {   // RNE f32->bf16 (low 16)
  unsigned u = __float_as_uint(f);
  u += 0x7fffu + ((u >> 16) & 1u);
  return u >> 16;
}
__device__ __forceinline__ float bf2f(unsigned short b) {
  return __uint_as_float(((unsigned)b) << 16);
}
// relaxed agent-scope ops -> global_load/store ... sc0 sc1 (device-coherent)
__device__ __forceinline__ void st8(void* p, u64 v) {
  __hip_atomic_store((u64*)p, v, __ATOMIC_RELAXED, __HIP_MEMORY_SCOPE_AGENT);
}
__device__ __forceinline__ unsigned ld4(const unsigned* p) {
  return __hip_atomic_load(p, __ATOMIC_RELAXED, __HIP_MEMORY_SCOPE_AGENT);
}
__device__ __forceinline__ void st4(unsigned* p, unsigned v) {
  __hip_atomic_store(p, v, __ATOMIC_RELAXED, __HIP_MEMORY_SCOPE_AGENT);
}
// invalidate this XCD's L2 (agent-acquire maintenance op; no operands/regs)
__device__ __forceinline__ void l2_inv() {
  asm volatile("buffer_inv sc1" ::: "memory");
}
// quad-perm broadcast
#define QB(x, imm) __uint_as_float((unsigned)__builtin_amdgcn_mov_dpp((int)__float_as_uint(x), imm, 0xF, 0xF, true))

struct KParams {
  const float *last_pos, *ch0, *w_hh;
  const float *se_w1, *se_b1, *se_g, *se_bt, *se_m, *se_v;
  const float *hp_w1, *hp_b1, *hp_g, *hp_bt, *hp_m, *hp_v, *hp_w2, *hp_b2;
  const float *W1f_g, *bias_f;
  char* hatom;            // 2 parities x 2 MB
  unsigned* flags;        // 16 x 32 u32
  float* out;
};

// ---------------------------------------------------------------------------
// Setup <<<320, 256>>>: blocks 0..255: W1f/bias (8 gate-rows each, LDS-staged,
// fully parallel dots). blocks 256..319: h0 -> atom layout (parity 1).
// ---------------------------------------------------------------------------
__global__ __launch_bounds__(256) void decoder_setup(
    const float* __restrict__ w_ih, const float* __restrict__ se_w2,
    const float* __restrict__ se_b2, const float* __restrict__ b_ih,
    const float* __restrict__ b_hh, const float* __restrict__ hh,
    float* __restrict__ W1f_g, float* __restrict__ bias_f,
    char* __restrict__ hatom) {
  int bid = blockIdx.x, tid = threadIdx.x;
  if (bid < 256) {
    __shared__ float wrow[8 * 512];
    __shared__ float ps[256];
    __shared__ float psB[128];
    int r0 = bid * 8;
    #pragma unroll
    for (int i = 0; i < 4; ++i) {
      int idx = i * 256 + tid;
      ((float4*)wrow)[idx] = ((const float4*)(w_ih + (size_t)r0 * 512))[idx];
    }
    __syncthreads();
    {
      int r = tid >> 5, q = (tid >> 1) & 15, half = tid & 1;
      const float* sw = se_w2 + (size_t)q * 512 + half * 256;
      const float* wr = wrow + r * 512 + half * 256;
      float s = 0.f;
      #pragma unroll 8
      for (int e = 0; e < 256; ++e) s += sw[e] * wr[e];
      ps[tid] = s;
    }
    if (tid < 128) {
      int r = tid >> 4, seg = tid & 15;
      const float* wr = wrow + r * 512 + seg * 32;
      const float* sb = se_b2 + seg * 32;
      float s = 0.f;
      #pragma unroll
      for (int e = 0; e < 32; ++e) s += sb[e] * wr[e];
      psB[tid] = s;
    }
    __syncthreads();
    if (tid < 128) {
      int r = tid >> 4, q = tid & 15;
      W1f_g[(r0 + r) * 16 + q] = ps[r * 32 + q * 2] + ps[r * 32 + q * 2 + 1];
    } else if (tid < 136) {
      int r = tid - 128;
      float s = 0.f;
      #pragma unroll
      for (int i = 0; i < 16; ++i) s += psB[r * 16 + i];
      bias_f[r0 + r] = s + b_ih[r0 + r] + b_hh[r0 + r];
    }
  } else {
    int bb = bid - 256;
    for (int u = 0; u < 8; ++u) {
      int aidx = bb * 2048 + u * 256 + tid;     // 131072 atoms total
      int mtl = aidx >> 13, a = aidx & 8191;
      int lane = a & 63, slot = a >> 6;
      int m = (slot & 3) * 32 + (lane & 31);
      int k8 = (slot >> 2) * 2 + (lane >> 5);
      const float* s8 = hh + (size_t)mtl * 65536 + (size_t)m * 512 + k8 * 8;
      uint4 v;
      v.x = f2bf(s8[0]) | (f2bf(s8[1]) << 16);
      v.y = f2bf(s8[2]) | (f2bf(s8[3]) << 16);
      v.z = f2bf(s8[4]) | (f2bf(s8[5]) << 16);
      v.w = f2bf(s8[6]) | (f2bf(s8[7]) << 16);
      *(uint4*)(hatom + 2097152 + (size_t)mtl * 131072 + (size_t)a * 16) = v;
    }
  }
}

// ---------------------------------------------------------------------------
// Persistent kernel. 256 blocks x 512 threads, 1 block/CU (plain launch).
// Block (mt, nt): rows [mt*128,+128), local n = 4*jj + gate.
// ---------------------------------------------------------------------------
__global__ __launch_bounds__(NTHR, 2) void decoder_persist(KParams p) {
  extern __shared__ char lds[];
  const int tid  = threadIdx.x;
  const int lane = tid & 63;
  const int wid  = tid >> 6;
  const int wm   = wid >> 1;
  const int wn   = wid & 1;
  const int mt   = blockIdx.x >> 4;
  const int nt   = blockIdx.x & 15;
  const int m0   = mt * 128;

  float* prm = (float*)(lds + PRM_OFF);
  float* lps = (float*)(lds + LPS_OFF);
  float* h2s = (float*)(lds + UNI_OFF);                   // stride 20 f32
  unsigned short* hPsh = (unsigned short*)(lds + UNI_OFF); // stride 36 u16
  unsigned short* h1s  = (unsigned short*)(lds + H1_OFF);  // stride 16 u16

  // ---------------- one-time init ----------------
  if (tid < 16) {
    int q = tid;
    float sA = p.se_g[q] * rsqrtf(p.se_v[q] + 1e-5f);
    prm[q]      = sA;
    prm[16 + q] = (p.se_b1[q] - p.se_m[q]) * sA + p.se_bt[q];
    float hA = p.hp_g[q] * rsqrtf(p.hp_v[q] + 1e-5f);
    prm[32 + q] = hA;
    prm[48 + q] = (p.hp_b1[q] - p.hp_m[q]) * hA + p.hp_bt[q];
  }
  if (tid < 32) { prm[64 + tid] = p.se_w1[tid]; prm[96 + tid] = p.hp_w2[tid]; }
  if (tid < 2)  { prm[128 + tid] = p.hp_b2[tid]; }
  if (tid < 256) lps[tid] = p.last_pos[(size_t)m0 * 2 + tid];
  float biasr[2];
  #pragma unroll
  for (int t2 = 0; t2 < 2; ++t2) {
    int n = wn * 64 + t2 * 32 + (lane & 31);
    int grow = (n & 3) * 512 + nt * 32 + (n >> 2);
    biasr[t2] = p.bias_f[grow];
  }
  // Bs: w_hh slice -> bf16 atoms (n, k8) at n*64 + (k8 ^ (n&7))
  for (int a = tid; a < 8192; a += NTHR) {
    int n = a >> 6, ka = a & 63;
    int grow = (n & 3) * 512 + nt * 32 + (n >> 2);
    const float* src = p.w_hh + (size_t)grow * 512 + ka * 8;
    uint4 v;
    v.x = f2bf(src[0]) | (f2bf(src[1]) << 16);
    v.y = f2bf(src[2]) | (f2bf(src[3]) << 16);
    v.z = f2bf(src[4]) | (f2bf(src[5]) << 16);
    v.w = f2bf(src[6]) | (f2bf(src[7]) << 16);
    *(uint4*)(lds + BS_OFF + ((size_t)(n * 64 + (ka ^ (n & 7)))) * 16) = v;
  }
  // hp_w1 atoms: atom (n<16, k8) = hp_w1[k8*8+j][n], j=0..7 (stride 16 floats)
  for (int a = tid; a < 1024; a += NTHR) {
    int n = a >> 6, k8 = a & 63;
    const float* src = p.hp_w1 + (size_t)(k8 * 8) * 16 + n;
    uint4 v;
    v.x = f2bf(src[0])   | (f2bf(src[16]) << 16);
    v.y = f2bf(src[32])  | (f2bf(src[48]) << 16);
    v.z = f2bf(src[64])  | (f2bf(src[80]) << 16);
    v.w = f2bf(src[96])  | (f2bf(src[112]) << 16);
    *(uint4*)(lds + HPW_OFF + ((size_t)(n * 64 + (k8 ^ (n & 7)))) * 16) = v;
  }
  // c state (lanes with lane%4==0), 16 rows x 2 tiles
  float c_st[2][16];
  #pragma unroll
  for (int t2 = 0; t2 < 2; ++t2)
    #pragma unroll
    for (int r = 0; r < 16; ++r) c_st[t2][r] = 0.f;
  if ((lane & 3) == 0) {
    #pragma unroll
    for (int t2 = 0; t2 < 2; ++t2) {
      int n_loc = wn * 64 + t2 * 32 + (lane & 31);
      int jj = n_loc >> 2;
      #pragma unroll
      for (int r = 0; r < 16; ++r) {
        int row = (r & 3) + 8 * (r >> 2) + 4 * (lane >> 5) + wm * 32;
        c_st[t2][r] = p.ch0[(size_t)(m0 + row) * 512 + nt * 32 + jj];
      }
    }
  }
  const int n0 = wn * 64 + (lane & 31);
  const int n1 = n0 + 32;
  const int gate = lane & 3;
  const int khalf = lane >> 5;
  const int pj = ((tid >> 8) << 1) | ((tid >> 5) & 1);
  const int pm = ((tid >> 6) & 3) * 32 + (tid & 31);
  // xg B-fragments (W1f) -> registers (K=16, constant all steps)
  union BW { unsigned short s[8]; bf16x8 v; } w0f, w1f;
  {
    int g0 = (n0 & 3) * 512 + nt * 32 + (n0 >> 2);
    int g1 = (n1 & 3) * 512 + nt * 32 + (n1 >> 2);
    const float4* s0 = (const float4*)(p.W1f_g + (size_t)g0 * 16 + khalf * 8);
    const float4* s1 = (const float4*)(p.W1f_g + (size_t)g1 * 16 + khalf * 8);
    float4 a = s0[0], b = s0[1], c = s1[0], d = s1[1];
    w0f.s[0] = f2bf(a.x); w0f.s[1] = f2bf(a.y); w0f.s[2] = f2bf(a.z); w0f.s[3] = f2bf(a.w);
    w0f.s[4] = f2bf(b.x); w0f.s[5] = f2bf(b.y); w0f.s[6] = f2bf(b.z); w0f.s[7] = f2bf(b.w);
    w1f.s[0] = f2bf(c.x); w1f.s[1] = f2bf(c.y); w1f.s[2] = f2bf(c.z); w1f.s[3] = f2bf(c.w);
    w1f.s[4] = f2bf(d.x); w1f.s[5] = f2bf(d.y); w1f.s[6] = f2bf(d.z); w1f.s[7] = f2bf(d.w);
  }
  __syncthreads();
  // one inv before the step loop: purge any cross-launch stale lines (poison)
  if (tid == 0) l2_inv();
  __syncthreads();
  // per-lane hp affine constants (q = lane&31 when <16)
  float sA2q = 0.f, bA2q = 0.f;
  if ((lane & 31) < 16) { sA2q = prm[32 + (lane & 31)]; bA2q = prm[48 + (lane & 31)]; }

  const unsigned* fl = p.flags + mt * 32 + (lane & 15);

  for (int t = 0; t < TSEQ; ++t) {
    // ---------- GEMM over h_t, fine-grained producer gating ----------
    f32x16 acc0, acc1, accP;
    #pragma unroll
    for (int i = 0; i < 16; ++i) { acc0[i] = 0.f; acc1[i] = 0.f; accP[i] = 0.f; }
    {
      const char* abase = p.hatom + (size_t)((t + 1) & 1) * 2097152 + mt * 131072
                          + (wm * 64 + lane) * 16;
      const unsigned tgt = (unsigned)t;
      u64 rdy = (t == 0) ? 0xffffull : (1ull << nt);   // own group always ready
      uint4 pre[DEPTH];
      #pragma unroll
      for (int j = 0; j < DEPTH; ++j) {
        int src = (nt + (j >> 1)) & 15;
        while (!((rdy >> src) & 1)) {
          rdy = __ballot(ld4(fl) >= tgt);
          __builtin_amdgcn_s_sleep(1);
        }
        pre[j] = *(const uint4*)(abase + ((src << 1) | (j & 1)) * 4096);
      }
      union AB { uint4 u; bf16x8 v; };
      #pragma unroll
      for (int j = 0; j < 32; ++j) {
        int c = (((nt + (j >> 1)) & 15) << 1) | (j & 1);
        AB u;
        u.u = pre[j & (DEPTH - 1)];
        int jn = j + DEPTH;
        if (jn < 32) {
          int srcn = (nt + (jn >> 1)) & 15;
          while (!((rdy >> srcn) & 1)) {
            rdy = __ballot(ld4(fl) >= tgt);
            __builtin_amdgcn_s_sleep(1);
          }
          pre[j & (DEPTH - 1)] =
              *(const uint4*)(abase + ((srcn << 1) | (jn & 1)) * 4096);
        }
        int kal = c * 2 + khalf;
        bf16x8 b0 = *(const bf16x8*)(lds + BS_OFF + (((n0 << 6) + (kal ^ (n0 & 7))) << 4));
        bf16x8 b1 = *(const bf16x8*)(lds + BS_OFF + (((n1 << 6) + (kal ^ (n1 & 7))) << 4));
        acc0 = __builtin_amdgcn_mfma_f32_32x32x16_bf16(u.v, b0, acc0, 0, 0, 0);
        acc1 = __builtin_amdgcn_mfma_f32_32x32x16_bf16(u.v, b1, acc1, 0, 0, 0);
        if (wn == 0) {
          bf16x8 bp = {};
          if ((lane & 31) < 16)
            bp = *(const bf16x8*)(lds + HPW_OFF
                  + ((((lane & 31) << 6) + (kal ^ (lane & 7))) << 4));
          accP = __builtin_amdgcn_mfma_f32_32x32x16_bf16(u.v, bp, accP, 0, 0, 0);
        }
      }
    }

    // ---------- lp_t from P (block-local); out[t-1] ----------
    if (t > 0) {
      if (wn == 0 && (lane & 31) < 16) {
        int q = lane & 31;
        #pragma unroll
        for (int r = 0; r < 16; ++r) {
          int row = (r & 3) + 8 * (r >> 2) + 4 * (lane >> 5) + wm * 32;
          h2s[row * 20 + q] = fmaxf(accP[r] * sA2q + bA2q, 0.f);
        }
      }
      __syncthreads();
      if (tid < 256) {
        int m = tid >> 1, c = tid & 1;
        float a2 = prm[128 + c];
        const float4* hrow = (const float4*)(lds + UNI_OFF + m * 80);
        #pragma unroll
        for (int g4 = 0; g4 < 4; ++g4) {
          float4 v = hrow[g4];
          a2 += v.x * prm[96 + (g4 * 4 + 0) * 2 + c];
          a2 += v.y * prm[96 + (g4 * 4 + 1) * 2 + c];
          a2 += v.z * prm[96 + (g4 * 4 + 2) * 2 + c];
          a2 += v.w * prm[96 + (g4 * 4 + 3) * 2 + c];
        }
        float lpv = 1.f / (1.f + __expf(-(a2 + lps[tid])));
        lps[tid] = lpv;
        if (nt == 0)
          st4((unsigned*)&p.out[((size_t)(t - 1) * BATCH + m0 + m) * 2 + c],
              __float_as_uint(lpv));
      }
      __syncthreads();
    }

    // ---------- h1 = relu(affine(lp @ se_w1)) ----------
    #pragma unroll
    for (int u = 0; u < 4; ++u) {
      int id = u * NTHR + tid;
      int m = id >> 4, q = id & 15;
      float z = lps[m * 2] * prm[64 + q] + lps[m * 2 + 1] * prm[80 + q];
      h1s[m * 16 + q] = (unsigned short)f2bf(fmaxf(z * prm[q] + prm[16 + q], 0.f));
    }
    __syncthreads();

    // ---------- xg contribution (last MFMA) ----------
    {
      bf16x8 a1 = *(const bf16x8*)(lds + H1_OFF + (wm * 32 + (lane & 31)) * 32 + khalf * 16);
      acc0 = __builtin_amdgcn_mfma_f32_32x32x16_bf16(a1, w0f.v, acc0, 0, 0, 0);
      acc1 = __builtin_amdgcn_mfma_f32_32x32x16_bf16(a1, w1f.v, acc1, 0, 0, 0);
    }

    // ---------- epilogue: LSTM cell update ----------
    #pragma unroll
    for (int t2 = 0; t2 < 2; ++t2) {
      float bias = biasr[t2];
      int jj = (wn * 64 + t2 * 32 + (lane & 31)) >> 2;
      float act[16];
      const f32x16& A = (t2 == 0) ? acc0 : acc1;
      #pragma unroll
      for (int r = 0; r < 16; ++r) {
        float v = A[r] + bias;
        float vv = (gate == 2) ? 2.f * v : v;
        float sg = 1.f / (1.f + __expf(-vv));
        act[r] = (gate == 2) ? 2.f * sg - 1.f : sg;
      }
      #pragma unroll
      for (int r = 0; r < 16; ++r) {
        float iv = QB(act[r], 0x00);
        float fv = QB(act[r], 0x55);
        float gv = QB(act[r], 0xAA);
        float ov = QB(act[r], 0xFF);
        float cn = fv * c_st[t2][r] + iv * gv;
        c_st[t2][r] = cn;
        float th = 2.f / (1.f + __expf(-2.f * cn)) - 1.f;
        float hn = ov * th;
        if ((lane & 3) == 0) {
          int row = (r & 3) + 8 * (r >> 2) + 4 * (lane >> 5) + wm * 32;
          hPsh[row * 36 + jj] = (unsigned short)f2bf(hn);
        }
      }
    }
    __syncthreads();

    // ---------- coalesced h-atom stores (sc0sc1 write-through) ----------
    {
      const u64* hp8 = (const u64*)(lds + UNI_OFF + pm * 72 + pj * 16);
      u64* hdst = (u64*)(p.hatom + (size_t)(t & 1) * 2097152 + mt * 131072);
      st8(hdst + (512 * nt + tid) * 2,     hp8[0]);
      st8(hdst + (512 * nt + tid) * 2 + 1, hp8[1]);
    }
    __syncthreads();   // implicit vmcnt(0) drains the sc1 stores
    if (wid == 0) {
      l2_inv();        // end-of-step inv: all our reads done; MALL is current
      if (lane == 0) st4(p.flags + mt * 32 + nt, (unsigned)(t + 1));
    }
  }

  // ---------- tail (t=32): P(h_32) only -> lp_32 -> out[31] ----------
  {
    if (wid == 0) {
      while (__ballot(ld4(fl) >= (unsigned)TSEQ) != ~0ull)
        __builtin_amdgcn_s_sleep(2);
    }
    __syncthreads();
    f32x16 accP;
    #pragma unroll
    for (int i = 0; i < 16; ++i) accP[i] = 0.f;
    if (wn == 0) {
      const char* abase = p.hatom + 2097152 + mt * 131072 + (wm * 64 + lane) * 16;
      uint4 pre[DEPTH];
      #pragma unroll
      for (int c = 0; c < DEPTH; ++c) pre[c] = *(const uint4*)(abase + c * 4096);
      union AB { uint4 u; bf16x8 v; };
      #pragma unroll
      for (int c = 0; c < 32; ++c) {
        AB u;
        u.u = pre[c & (DEPTH - 1)];
        if (c + DEPTH < 32)
          pre[c & (DEPTH - 1)] = *(const uint4*)(abase + (c + DEPTH) * 4096);
        int kal = c * 2 + khalf;
        bf16x8 bp = {};
        if ((lane & 31) < 16)
          bp = *(const bf16x8*)(lds + HPW_OFF
                + ((((lane & 31) << 6) + (kal ^ (lane & 7))) << 4));
        accP = __builtin_amdgcn_mfma_f32_32x32x16_bf16(u.v, bp, accP, 0, 0, 0);
      }
      if ((lane & 31) < 16) {
        int q = lane & 31;
        #pragma unroll
        for (int r = 0; r < 16; ++r) {
          int row = (r & 3) + 8 * (r >> 2) + 4 * (lane >> 5) + wm * 32;
          h2s[row * 20 + q] = fmaxf(accP[r] * sA2q + bA2q, 0.f);
        }
      }
    }
    __syncthreads();
    if (tid < 256 && nt == 0) {
      int m = tid >> 1, c = tid & 1;
      float a2 = prm[128 + c];
      const float4* hrow = (const float4*)(lds + UNI_OFF + m * 80);
      #pragma unroll
      for (int g4 = 0; g4 < 4; ++g4) {
        float4 v = hrow[g4];
        a2 += v.x * prm[96 + (g4 * 4 + 0) * 2 + c];
        a2 += v.y * prm[96 + (g4 * 4 + 1) * 2 + c];
        a2 += v.z * prm[96 + (g4 * 4 + 2) * 2 + c];
        a2 += v.w * prm[96 + (g4 * 4 + 3) * 2 + c];
      }
      float lpv = 1.f / (1.f + __expf(-(a2 + lps[tid])));
      st4((unsigned*)&p.out[((size_t)(TSEQ - 1) * BATCH + m0 + m) * 2 + c],
          __float_as_uint(lpv));
    }
  }
}

// ---------------------------------------------------------------------------
extern "C" void kernel_launch(void* const* d_in, const int* in_sizes, int n_in,
                              void* d_out, int out_size, void* d_ws, size_t ws_size,
                              hipStream_t stream) {
  char* ws = (char*)d_ws;
  const float* last_pos = (const float*)d_in[0];
  const float* hh    = (const float*)d_in[1];
  const float* ch    = (const float*)d_in[2];
  const float* se_w1 = (const float*)d_in[3];
  const float* se_b1 = (const float*)d_in[4];
  const float* se_g  = (const float*)d_in[5];
  const float* se_bt = (const float*)d_in[6];
  const float* se_m  = (const float*)d_in[7];
  const float* se_v  = (const float*)d_in[8];
  const float* se_w2 = (const float*)d_in[9];
  const float* se_b2 = (const float*)d_in[10];
  const float* w_ih  = (const float*)d_in[11];
  const float* w_hh  = (const float*)d_in[12];
  const float* b_ih  = (const float*)d_in[13];
  const float* b_hh  = (const float*)d_in[14];
  const float* hp_w1 = (const float*)d_in[15];
  const float* hp_b1 = (const float*)d_in[16];
  const float* hp_g  = (const float*)d_in[17];
  const float* hp_bt = (const float*)d_in[18];
  const float* hp_m  = (const float*)d_in[19];
  const float* hp_v  = (const float*)d_in[20];
  const float* hp_w2 = (const float*)d_in[21];
  const float* hp_b2 = (const float*)d_in[22];

  float* W1f_g  = (float*)(ws + WS_W1F);
  float* bias_f = (float*)(ws + WS_BIASF);
  unsigned* flags = (unsigned*)(ws + WS_FLAGS);
  char* hatom   = ws + WS_HATOM;

  (void)hipMemsetAsync(ws + WS_FLAGS, 0, 2048, stream);
  decoder_setup<<<dim3(320), dim3(256), 0, stream>>>(
      w_ih, se_w2, se_b2, b_ih, b_hh, hh, W1f_g, bias_f, hatom);

  (void)hipFuncSetAttribute((const void*)decoder_persist,
                            hipFuncAttributeMaxDynamicSharedMemorySize, LDS_TOTAL);

  KParams kp;
  kp.last_pos = last_pos; kp.ch0 = ch; kp.w_hh = w_hh;
  kp.se_w1 = se_w1; kp.se_b1 = se_b1; kp.se_g = se_g; kp.se_bt = se_bt;
  kp.se_m = se_m; kp.se_v = se_v;
  kp.hp_w1 = hp_w1; kp.hp_b1 = hp_b1; kp.hp_g = hp_g; kp.hp_bt = hp_bt;
  kp.hp_m = hp_m; kp.hp_v = hp_v; kp.hp_w2 = hp_w2; kp.hp_b2 = hp_b2;
  kp.W1f_g = W1f_g; kp.bias_f = bias_f;
  kp.hatom = hatom; kp.flags = flags; kp.out = (float*)d_out;

  // Plain launch: 256 blocks x 1/CU (exact fit) — flags need co-residency only.
  decoder_persist<<<dim3(NBLK), dim3(NTHR), LDS_TOTAL, stream>>>(kp);
}

// Round 10
// 526.639 us; speedup vs baseline: 2.9835x; 1.1147x over previous
//
#include <hip/hip_runtime.h>

// ============================================================================
// Decoder_70437463654609: 32-step LSTM recurrence, B=2048 H=512 HID=16.
// R10 = R8 GEMM/barrier (cached A + wait-all + inv, DEPTH 8, plain launch)
//  + setup folded into persist init (init-MFMA computes W1f/bias; h0 atoms
//    written by each block for its own region; flags shifted +1)
//  + merged lp/h1 phase via DPP pair swap (one less sync per step).
// Graph = memset(flags) + persist only.
// ============================================================================

#define TSEQ  32
#define BATCH 2048
#define HDIM  512
#define NBLK  256
#define NTHR  512
#define DEPTH 8

typedef __bf16 bf16x8 __attribute__((ext_vector_type(8)));
typedef float  f32x16 __attribute__((ext_vector_type(16)));
typedef unsigned long long u64;

// ---- LDS layout (byte offsets), total 163,360 <= 163,840 ----
#define BS_OFF     0          // Bs: w_hh [128 n][64 k8 x 16B] swz (131072); init: B-atoms(32KB)+W1T+bT
#define HPW_OFF    131072     // hp_w1 atoms [16 n][64 k8 x 16B] swz (16384)
#define UNI_OFF    147456     // union: h2s [128][20] f32 (10240) | hP bf16 [128][36] (9216)
#define H1_OFF     157696     // h1s [128 m][16 bf16] stride 32 B (4096)
#define LPS_OFF    161792     // lps [128][2] f32 (1024)
#define PRM_OFF    162816     // folded params (130 f32) (544)
#define LDS_TOTAL  163360
// init-phase temporaries inside the Bs region:
#define W1T_OFF    32768      // [128][17] f32 (8704)
#define BT_OFF     41472      // [128] f32 (512)

// ---- workspace layout (bytes) ----
#define WS_FLAGS  0                        // 16 groups x 128 B (memset to 0)
#define WS_HATOM  2048                     // 2 x (16 mt x 128 KB) h atoms

__device__ __forceinline__ unsigned f2bf(float f) {   // RNE f32->bf16 (low 16)
  unsigned u = __float_as_uint(f);
  u += 0x7fffu + ((u >> 16) & 1u);
  return u >> 16;
}
// relaxed agent-scope ops -> global_load/store ... sc0 sc1 (device-coherent)
__device__ __forceinline__ void st8(void* p, u64 v) {
  __hip_atomic_store((u64*)p, v, __ATOMIC_RELAXED, __HIP_MEMORY_SCOPE_AGENT);
}
__device__ __forceinline__ unsigned ld4(const unsigned* p) {
  return __hip_atomic_load(p, __ATOMIC_RELAXED, __HIP_MEMORY_SCOPE_AGENT);
}
__device__ __forceinline__ void st4(unsigned* p, unsigned v) {
  __hip_atomic_store(p, v, __ATOMIC_RELAXED, __HIP_MEMORY_SCOPE_AGENT);
}
__device__ __forceinline__ void l2_inv() {
  asm volatile("buffer_inv sc1" ::: "memory");
}
// quad-perm broadcasts / swaps
#define QB(x, imm) __uint_as_float((unsigned)__builtin_amdgcn_mov_dpp((int)__float_as_uint(x), imm, 0xF, 0xF, true))

struct KParams {
  const float *last_pos, *hh, *ch0, *w_hh, *w_ih, *b_ih, *b_hh;
  const float *se_w1, *se_b1, *se_g, *se_bt, *se_m, *se_v, *se_w2, *se_b2;
  const float *hp_w1, *hp_b1, *hp_g, *hp_bt, *hp_m, *hp_v, *hp_w2, *hp_b2;
  char* hatom;            // 2 parities x 2 MB
  unsigned* flags;        // 16 x 32 u32
  float* out;
};

// ---------------------------------------------------------------------------
// Persistent kernel. 256 blocks x 512 threads, 1 block/CU (plain launch).
// Block (mt, nt): rows [mt*128,+128), local n = 4*jj + gate.
// ---------------------------------------------------------------------------
__global__ __launch_bounds__(NTHR, 2) void decoder_persist(KParams p) {
  extern __shared__ char lds[];
  const int tid  = threadIdx.x;
  const int lane = tid & 63;
  const int wid  = tid >> 6;
  const int wm   = wid >> 1;
  const int wn   = wid & 1;
  const int mt   = blockIdx.x >> 4;
  const int nt   = blockIdx.x & 15;
  const int m0   = mt * 128;

  float* prm = (float*)(lds + PRM_OFF);
  float* lps = (float*)(lds + LPS_OFF);
  float* h2s = (float*)(lds + UNI_OFF);                    // stride 20 f32
  unsigned short* hPsh = (unsigned short*)(lds + UNI_OFF); // stride 36 u16
  float* W1T = (float*)(lds + W1T_OFF);                    // [128][17]
  float* bT  = (float*)(lds + BT_OFF);                     // [128]

  const int n0 = wn * 64 + (lane & 31);
  const int n1 = n0 + 32;
  const int gate = lane & 3;
  const int khalf = lane >> 5;
  const int pj = ((tid >> 8) << 1) | ((tid >> 5) & 1);
  const int pm = ((tid >> 6) & 3) * 32 + (tid & 31);

  // ================= one-time init =================
  if (tid < 16) {
    int q = tid;
    float sA = p.se_g[q] * rsqrtf(p.se_v[q] + 1e-5f);
    prm[q]      = sA;
    prm[16 + q] = (p.se_b1[q] - p.se_m[q]) * sA + p.se_bt[q];
    float hA = p.hp_g[q] * rsqrtf(p.hp_v[q] + 1e-5f);
    prm[32 + q] = hA;
    prm[48 + q] = (p.hp_b1[q] - p.hp_m[q]) * hA + p.hp_bt[q];
  }
  if (tid < 32) { prm[64 + tid] = p.se_w1[tid]; prm[96 + tid] = p.hp_w2[tid]; }
  if (tid < 2)  { prm[128 + tid] = p.hp_b2[tid]; }
  if (tid < 256) lps[tid] = p.last_pos[(size_t)m0 * 2 + tid];

  // ---- stage init B-atoms: cols 0..15 = se_w2 rows, 16 = se_b2, 17..31 = 0
  for (int a = tid; a < 2048; a += NTHR) {
    int n = a >> 6, k8 = a & 63;
    uint4 v = {0, 0, 0, 0};
    if (n <= 16) {
      const float* src = (n < 16) ? (p.se_w2 + (size_t)n * 512 + k8 * 8)
                                  : (p.se_b2 + k8 * 8);
      v.x = f2bf(src[0]) | (f2bf(src[1]) << 16);
      v.y = f2bf(src[2]) | (f2bf(src[3]) << 16);
      v.z = f2bf(src[4]) | (f2bf(src[5]) << 16);
      v.w = f2bf(src[6]) | (f2bf(src[7]) << 16);
    }
    *(uint4*)(lds + BS_OFF + ((size_t)(n * 64 + (k8 ^ (n & 7)))) * 16) = v;
  }
  __syncthreads();

  // ---- init-MFMA: W1f[128 gate-rows][16] = w_ih_slice @ se_w2^T (+bias col 16)
  if ((wid & 1) == 0) {
    int rloc = wm * 32 + (lane & 31);
    int grow = (rloc & 3) * 512 + nt * 32 + (rloc >> 2);
    const float* arow = p.w_ih + (size_t)grow * 512;
    f32x16 accW;
    #pragma unroll
    for (int i = 0; i < 16; ++i) accW[i] = 0.f;
    float4 pa[4], pb[4];
    #pragma unroll
    for (int j = 0; j < 4; ++j) {
      int kal = j * 2 + khalf;
      pa[j] = ((const float4*)(arow + kal * 8))[0];
      pb[j] = ((const float4*)(arow + kal * 8))[1];
    }
    #pragma unroll
    for (int c = 0; c < 32; ++c) {
      int kal = c * 2 + khalf;
      union { unsigned short s[8]; bf16x8 v; } av;
      float4 a = pa[c & 3], b = pb[c & 3];
      av.s[0] = f2bf(a.x); av.s[1] = f2bf(a.y); av.s[2] = f2bf(a.z); av.s[3] = f2bf(a.w);
      av.s[4] = f2bf(b.x); av.s[5] = f2bf(b.y); av.s[6] = f2bf(b.z); av.s[7] = f2bf(b.w);
      if (c + 4 < 32) {
        int kn = (c + 4) * 2 + khalf;
        pa[c & 3] = ((const float4*)(arow + kn * 8))[0];
        pb[c & 3] = ((const float4*)(arow + kn * 8))[1];
      }
      int q = lane & 31;
      bf16x8 bp = *(const bf16x8*)(lds + BS_OFF + (((q << 6) + (kal ^ (q & 7))) << 4));
      accW = __builtin_amdgcn_mfma_f32_32x32x16_bf16(av.v, bp, accW, 0, 0, 0);
    }
    int q = lane & 31;
    #pragma unroll
    for (int r = 0; r < 16; ++r) {
      int row = (r & 3) + 8 * (r >> 2) + 4 * khalf + wm * 32;
      if (q < 16) {
        W1T[row * 17 + q] = accW[r];
      } else if (q == 16) {
        int g2 = (row & 3) * 512 + nt * 32 + (row >> 2);
        bT[row] = accW[r] + p.b_ih[g2] + p.b_hh[g2];
      }
    }
  }
  __syncthreads();

  // ---- read xg fragments + bias from LDS temps; convert h0 atoms
  union BW { unsigned short s[8]; bf16x8 v; } w0f, w1f;
  #pragma unroll
  for (int j = 0; j < 8; ++j) {
    w0f.s[j] = (unsigned short)f2bf(W1T[n0 * 17 + khalf * 8 + j]);
    w1f.s[j] = (unsigned short)f2bf(W1T[n1 * 17 + khalf * 8 + j]);
  }
  float biasr[2];
  biasr[0] = bT[wn * 64 + (lane & 31)];
  biasr[1] = bT[wn * 64 + 32 + (lane & 31)];
  {
    // h0 -> parity-1 atoms, exactly this block's store region
    const float* src = p.hh + (size_t)(m0 + pm) * 512 + nt * 32 + pj * 8;
    float4 f0 = ((const float4*)src)[0];
    float4 f1 = ((const float4*)src)[1];
    u64 lo = (u64)f2bf(f0.x) | ((u64)f2bf(f0.y) << 16)
           | ((u64)f2bf(f0.z) << 32) | ((u64)f2bf(f0.w) << 48);
    u64 hi = (u64)f2bf(f1.x) | ((u64)f2bf(f1.y) << 16)
           | ((u64)f2bf(f1.z) << 32) | ((u64)f2bf(f1.w) << 48);
    u64* hdst = (u64*)(p.hatom + 2097152 + mt * 131072);
    st8(hdst + (512 * nt + tid) * 2,     lo);
    st8(hdst + (512 * nt + tid) * 2 + 1, hi);
  }
  __syncthreads();                      // drains h0 st8 (vmcnt before barrier)
  if (tid == 0) st4(p.flags + mt * 32 + nt, 1u);

  // ---- Bs: w_hh slice -> bf16 atoms (overwrite init temps)
  for (int a = tid; a < 8192; a += NTHR) {
    int n = a >> 6, ka = a & 63;
    int grow = (n & 3) * 512 + nt * 32 + (n >> 2);
    const float* src = p.w_hh + (size_t)grow * 512 + ka * 8;
    uint4 v;
    v.x = f2bf(src[0]) | (f2bf(src[1]) << 16);
    v.y = f2bf(src[2]) | (f2bf(src[3]) << 16);
    v.z = f2bf(src[4]) | (f2bf(src[5]) << 16);
    v.w = f2bf(src[6]) | (f2bf(src[7]) << 16);
    *(uint4*)(lds + BS_OFF + ((size_t)(n * 64 + (ka ^ (n & 7)))) * 16) = v;
  }
  // hp_w1 atoms: atom (n<16, k8) = hp_w1[k8*8+j][n]
  for (int a = tid; a < 1024; a += NTHR) {
    int n = a >> 6, k8 = a & 63;
    const float* src = p.hp_w1 + (size_t)(k8 * 8) * 16 + n;
    uint4 v;
    v.x = f2bf(src[0])  | (f2bf(src[16]) << 16);
    v.y = f2bf(src[32]) | (f2bf(src[48]) << 16);
    v.z = f2bf(src[64]) | (f2bf(src[80]) << 16);
    v.w = f2bf(src[96]) | (f2bf(src[112]) << 16);
    *(uint4*)(lds + HPW_OFF + ((size_t)(n * 64 + (k8 ^ (n & 7)))) * 16) = v;
  }
  // c state (lanes with lane%4==0)
  float c_st[2][16];
  #pragma unroll
  for (int t2 = 0; t2 < 2; ++t2)
    #pragma unroll
    for (int r = 0; r < 16; ++r) c_st[t2][r] = 0.f;
  if ((lane & 3) == 0) {
    #pragma unroll
    for (int t2 = 0; t2 < 2; ++t2) {
      int jj = (wn * 64 + t2 * 32 + (lane & 31)) >> 2;
      #pragma unroll
      for (int r = 0; r < 16; ++r) {
        int row = (r & 3) + 8 * (r >> 2) + 4 * khalf + wm * 32;
        c_st[t2][r] = p.ch0[(size_t)(m0 + row) * 512 + nt * 32 + jj];
      }
    }
  }
  __syncthreads();

  float sA2q = 0.f, bA2q = 0.f;
  if ((lane & 31) < 16) { sA2q = prm[32 + (lane & 31)]; bA2q = prm[48 + (lane & 31)]; }
  const unsigned* fl = p.flags + mt * 32 + (lane & 15);

  // ================= main loop =================
  for (int t = 0; t < TSEQ; ++t) {
    if (wid == 0) {
      while (!__all((int)(ld4(fl) >= (unsigned)(t + 1))))
        __builtin_amdgcn_s_sleep(2);
      l2_inv();          // purge stale A lines; MALL is current (sc1 writes)
    }
    __syncthreads();

    // ---------- GEMM over h_t: gates (acc0,acc1) + P (accP, wn==0) ----------
    f32x16 acc0, acc1, accP;
    #pragma unroll
    for (int i = 0; i < 16; ++i) { acc0[i] = 0.f; acc1[i] = 0.f; accP[i] = 0.f; }
    {
      const char* abase = p.hatom + (size_t)((t + 1) & 1) * 2097152 + mt * 131072
                          + (wm * 64 + lane) * 16;
      uint4 pre[DEPTH];
      #pragma unroll
      for (int c = 0; c < DEPTH; ++c) pre[c] = *(const uint4*)(abase + c * 4096);
      union AB { uint4 u; bf16x8 v; };
      #pragma unroll
      for (int c = 0; c < 32; ++c) {
        AB u;
        u.u = pre[c & (DEPTH - 1)];
        if (c + DEPTH < 32)
          pre[c & (DEPTH - 1)] = *(const uint4*)(abase + (c + DEPTH) * 4096);
        int kal = c * 2 + khalf;
        bf16x8 b0 = *(const bf16x8*)(lds + BS_OFF + (((n0 << 6) + (kal ^ (n0 & 7))) << 4));
        bf16x8 b1 = *(const bf16x8*)(lds + BS_OFF + (((n1 << 6) + (kal ^ (n1 & 7))) << 4));
        acc0 = __builtin_amdgcn_mfma_f32_32x32x16_bf16(u.v, b0, acc0, 0, 0, 0);
        acc1 = __builtin_amdgcn_mfma_f32_32x32x16_bf16(u.v, b1, acc1, 0, 0, 0);
        if (wn == 0) {
          bf16x8 bp = {};
          if ((lane & 31) < 16)
            bp = *(const bf16x8*)(lds + HPW_OFF
                  + ((((lane & 31) << 6) + (kal ^ (lane & 7))) << 4));
          accP = __builtin_amdgcn_mfma_f32_32x32x16_bf16(u.v, bp, accP, 0, 0, 0);
        }
      }
    }

    // ---------- P -> h2s (wn==0 waves) ----------
    if (t > 0) {
      if (wn == 0 && (lane & 31) < 16) {
        int q = lane & 31;
        #pragma unroll
        for (int r = 0; r < 16; ++r) {
          int row = (r & 3) + 8 * (r >> 2) + 4 * khalf + wm * 32;
          h2s[row * 20 + q] = fmaxf(accP[r] * sA2q + bA2q, 0.f);
        }
      }
      __syncthreads();
    }

    // ---------- merged lp + h1 (threads < 256; DPP pair swap) ----------
    if (tid < 256) {
      int m = tid >> 1, c = tid & 1;
      float lp0, lp1;
      if (t > 0) {
        float a2 = prm[128 + c];
        const float4* hrow = (const float4*)(lds + UNI_OFF + m * 80);
        #pragma unroll
        for (int g4 = 0; g4 < 4; ++g4) {
          float4 v = hrow[g4];
          a2 += v.x * prm[96 + (g4 * 4 + 0) * 2 + c];
          a2 += v.y * prm[96 + (g4 * 4 + 1) * 2 + c];
          a2 += v.z * prm[96 + (g4 * 4 + 2) * 2 + c];
          a2 += v.w * prm[96 + (g4 * 4 + 3) * 2 + c];
        }
        float lpv = 1.f / (1.f + __expf(-(a2 + lps[tid])));
        lps[tid] = lpv;
        if (nt == 0)
          st4((unsigned*)&p.out[((size_t)(t - 1) * BATCH + m0 + m) * 2 + c],
              __float_as_uint(lpv));
        float other = QB(lpv, 0xB1);                   // swap within lane pair
        lp0 = c ? other : lpv;
        lp1 = c ? lpv : other;
      } else {
        lp0 = lps[m * 2];
        lp1 = lps[m * 2 + 1];
      }
      // h1 for q = c*8 .. c*8+7, packed 16 B store
      u64 hq[2];
      #pragma unroll
      for (int half = 0; half < 2; ++half) {
        u64 w = 0;
        #pragma unroll
        for (int i = 0; i < 4; ++i) {
          int q = c * 8 + half * 4 + i;
          float z = lp0 * prm[64 + q] + lp1 * prm[80 + q];
          w |= (u64)f2bf(fmaxf(z * prm[q] + prm[16 + q], 0.f)) << (16 * i);
        }
        hq[half] = w;
      }
      u64* hd = (u64*)(lds + H1_OFF + m * 32 + c * 16);
      hd[0] = hq[0];
      hd[1] = hq[1];
    }
    __syncthreads();

    // ---------- xg contribution (last MFMA) ----------
    {
      bf16x8 a1 = *(const bf16x8*)(lds + H1_OFF + (wm * 32 + (lane & 31)) * 32 + khalf * 16);
      acc0 = __builtin_amdgcn_mfma_f32_32x32x16_bf16(a1, w0f.v, acc0, 0, 0, 0);
      acc1 = __builtin_amdgcn_mfma_f32_32x32x16_bf16(a1, w1f.v, acc1, 0, 0, 0);
    }

    // ---------- epilogue: LSTM cell update ----------
    #pragma unroll
    for (int t2 = 0; t2 < 2; ++t2) {
      float bias = biasr[t2];
      int jj = (wn * 64 + t2 * 32 + (lane & 31)) >> 2;
      float act[16];
      const f32x16& A = (t2 == 0) ? acc0 : acc1;
      #pragma unroll
      for (int r = 0; r < 16; ++r) {
        float v = A[r] + bias;
        float vv = (gate == 2) ? 2.f * v : v;
        float sg = 1.f / (1.f + __expf(-vv));
        act[r] = (gate == 2) ? 2.f * sg - 1.f : sg;
      }
      #pragma unroll
      for (int r = 0; r < 16; ++r) {
        float iv = QB(act[r], 0x00);
        float fv = QB(act[r], 0x55);
        float gv = QB(act[r], 0xAA);
        float ov = QB(act[r], 0xFF);
        float cn = fv * c_st[t2][r] + iv * gv;
        c_st[t2][r] = cn;
        float th = 2.f / (1.f + __expf(-2.f * cn)) - 1.f;
        float hn = ov * th;
        if ((lane & 3) == 0) {
          int row = (r & 3) + 8 * (r >> 2) + 4 * khalf + wm * 32;
          hPsh[row * 36 + jj] = (unsigned short)f2bf(hn);
        }
      }
    }
    __syncthreads();

    // ---------- coalesced h-atom stores (sc0sc1 write-through) + flag ----------
    {
      const u64* hp8 = (const u64*)(lds + UNI_OFF + pm * 72 + pj * 16);
      u64* hdst = (u64*)(p.hatom + (size_t)(t & 1) * 2097152 + mt * 131072);
      st8(hdst + (512 * nt + tid) * 2,     hp8[0]);
      st8(hdst + (512 * nt + tid) * 2 + 1, hp8[1]);
    }
    __syncthreads();   // implicit vmcnt(0) drains the sc1 stores
    if (tid == 0) st4(p.flags + mt * 32 + nt, (unsigned)(t + 2));
  }

  // ---------- tail (t=32): P(h_32) only -> lp_32 -> out[31] ----------
  {
    if (wid == 0) {
      while (!__all((int)(ld4(fl) >= (unsigned)(TSEQ + 1))))
        __builtin_amdgcn_s_sleep(2);
      l2_inv();
    }
    __syncthreads();
    f32x16 accP;
    #pragma unroll
    for (int i = 0; i < 16; ++i) accP[i] = 0.f;
    if (wn == 0) {
      const char* abase = p.hatom + 2097152 + mt * 131072 + (wm * 64 + lane) * 16;
      uint4 pre[DEPTH];
      #pragma unroll
      for (int c = 0; c < DEPTH; ++c) pre[c] = *(const uint4*)(abase + c * 4096);
      union AB { uint4 u; bf16x8 v; };
      #pragma unroll
      for (int c = 0; c < 32; ++c) {
        AB u;
        u.u = pre[c & (DEPTH - 1)];
        if (c + DEPTH < 32)
          pre[c & (DEPTH - 1)] = *(const uint4*)(abase + (c + DEPTH) * 4096);
        int kal = c * 2 + khalf;
        bf16x8 bp = {};
        if ((lane & 31) < 16)
          bp = *(const bf16x8*)(lds + HPW_OFF
                + ((((lane & 31) << 6) + (kal ^ (lane & 7))) << 4));
        accP = __builtin_amdgcn_mfma_f32_32x32x16_bf16(u.v, bp, accP, 0, 0, 0);
      }
      if ((lane & 31) < 16) {
        int q = lane & 31;
        #pragma unroll
        for (int r = 0; r < 16; ++r) {
          int row = (r & 3) + 8 * (r >> 2) + 4 * khalf + wm * 32;
          h2s[row * 20 + q] = fmaxf(accP[r] * sA2q + bA2q, 0.f);
        }
      }
    }
    __syncthreads();
    if (tid < 256 && nt == 0) {
      int m = tid >> 1, c = tid & 1;
      float a2 = prm[128 + c];
      const float4* hrow = (const float4*)(lds + UNI_OFF + m * 80);
      #pragma unroll
      for (int g4 = 0; g4 < 4; ++g4) {
        float4 v = hrow[g4];
        a2 += v.x * prm[96 + (g4 * 4 + 0) * 2 + c];
        a2 += v.y * prm[96 + (g4 * 4 + 1) * 2 + c];
        a2 += v.z * prm[96 + (g4 * 4 + 2) * 2 + c];
        a2 += v.w * prm[96 + (g4 * 4 + 3) * 2 + c];
      }
      float lpv = 1.f / (1.f + __expf(-(a2 + lps[tid])));
      st4((unsigned*)&p.out[((size_t)(TSEQ - 1) * BATCH + m0 + m) * 2 + c],
          __float_as_uint(lpv));
    }
  }
}

// ---------------------------------------------------------------------------
extern "C" void kernel_launch(void* const* d_in, const int* in_sizes, int n_in,
                              void* d_out, int out_size, void* d_ws, size_t ws_size,
                              hipStream_t stream) {
  char* ws = (char*)d_ws;
  KParams kp;
  kp.last_pos = (const float*)d_in[0];
  kp.hh    = (const float*)d_in[1];
  kp.ch0   = (const float*)d_in[2];
  kp.se_w1 = (const float*)d_in[3];
  kp.se_b1 = (const float*)d_in[4];
  kp.se_g  = (const float*)d_in[5];
  kp.se_bt = (const float*)d_in[6];
  kp.se_m  = (const float*)d_in[7];
  kp.se_v  = (const float*)d_in[8];
  kp.se_w2 = (const float*)d_in[9];
  kp.se_b2 = (const float*)d_in[10];
  kp.w_ih  = (const float*)d_in[11];
  kp.w_hh  = (const float*)d_in[12];
  kp.b_ih  = (const float*)d_in[13];
  kp.b_hh  = (const float*)d_in[14];
  kp.hp_w1 = (const float*)d_in[15];
  kp.hp_b1 = (const float*)d_in[16];
  kp.hp_g  = (const float*)d_in[17];
  kp.hp_bt = (const float*)d_in[18];
  kp.hp_m  = (const float*)d_in[19];
  kp.hp_v  = (const float*)d_in[20];
  kp.hp_w2 = (const float*)d_in[21];
  kp.hp_b2 = (const float*)d_in[22];
  kp.flags = (unsigned*)(ws + WS_FLAGS);
  kp.hatom = ws + WS_HATOM;
  kp.out   = (float*)d_out;

  (void)hipMemsetAsync(ws + WS_FLAGS, 0, 2048, stream);
  (void)hipFuncSetAttribute((const void*)decoder_persist,
                            hipFuncAttributeMaxDynamicSharedMemorySize, LDS_TOTAL);
  decoder_persist<<<dim3(NBLK), dim3(NTHR), LDS_TOTAL, stream>>>(kp);
}